// Round 3
// baseline (453.739 us; speedup 1.0000x reference)
//
#include <hip/hip_runtime.h>
#include <math.h>

typedef unsigned short u16;
typedef __bf16 bf16x8 __attribute__((ext_vector_type(8)));
typedef __bf16 bf16x4 __attribute__((ext_vector_type(4)));
typedef u16 u16x4 __attribute__((ext_vector_type(4)));
typedef float f32x4 __attribute__((ext_vector_type(4)));

// ---- constants ----
// B=4, N=1024, D=768, H=12, Dh=64, HID=2048, 3D=2304
#define NTOK 1024
#define DMODEL 768
#define NHEAD 12
#define LD3 2304
#define HIDDIM 2048

__device__ __forceinline__ float b2f(u16 u) {
  unsigned int t = ((unsigned int)u) << 16;
  float f;
  __builtin_memcpy(&f, &t, 4);
  return f;
}
__device__ __forceinline__ u16 f2b(float f) {
  unsigned int t;
  __builtin_memcpy(&t, &f, 4);
  t += 0x7fffu + ((t >> 16) & 1u);
  return (u16)(t >> 16);
}

// ---------------- host-assert signal (f32 output now) ------------------------
__global__ __launch_bounds__(256) void signal_kernel(float* __restrict__ out,
                                                     int n, float c) {
  int i = blockIdx.x * 256 + threadIdx.x;
  if (i < n) out[i] = c;
}

// ---------------- input dtype detection (verified f32: flag=1, R6) -----------
__global__ __launch_bounds__(256) void detect_kernel(const u16* __restrict__ x,
                                                     int* __restrict__ flag) {
  __shared__ int cnt;
  if (threadIdx.x == 0) cnt = 0;
  __syncthreads();
  int bad = 0;
  for (int i = threadIdx.x; i < 4096; i += 256) {
    u16 v = x[2 * i];
    int e = (v >> 7) & 0xFF;
    if (e >= 0xC0) bad++;
  }
  atomicAdd(&cnt, bad);
  __syncthreads();
  if (threadIdx.x == 0) *flag = (cnt >= 64) ? 1 : 0;
}

// ---------------- canonicalize all inputs to bf16 (linear, C-order) ----------
struct CanonJobs {
  const void* s[13];
  u16* d[13];
  int n[13];
};

__global__ __launch_bounds__(256) void canon_kernel(CanonJobs jobs,
                                                    const int* __restrict__ flag) {
  int j = blockIdx.y;
  int n = jobs.n[j];
  const void* s = jobs.s[j];
  u16* d = jobs.d[j];
  bool isf32 = (*flag != 0);
  for (int i = blockIdx.x * 256 + threadIdx.x; i < n; i += gridDim.x * 256) {
    d[i] = isf32 ? f2b(((const float*)s)[i]) : ((const u16*)s)[i];
  }
}

// ---------------- LayerNorm (bf16 input) ----------------
__global__ __launch_bounds__(256) void ln_bf16_kernel(
    const u16* __restrict__ x, const u16* __restrict__ g,
    const u16* __restrict__ b, u16* __restrict__ out) {
  int row = blockIdx.x;
  int tid = threadIdx.x;
  const u16* xr = x + (size_t)row * DMODEL;
  float v0 = b2f(xr[tid]), v1 = b2f(xr[tid + 256]), v2 = b2f(xr[tid + 512]);
  float s = v0 + v1 + v2;
  float q = v0 * v0 + v1 * v1 + v2 * v2;
#pragma unroll
  for (int off = 32; off; off >>= 1) {
    s += __shfl_xor(s, off, 64);
    q += __shfl_xor(q, off, 64);
  }
  __shared__ float rs[4], rq[4];
  int wv = tid >> 6;
  if ((tid & 63) == 0) { rs[wv] = s; rq[wv] = q; }
  __syncthreads();
  s = rs[0] + rs[1] + rs[2] + rs[3];
  q = rq[0] + rq[1] + rq[2] + rq[3];
  float mean = s * (1.0f / 768.0f);
  float var = q * (1.0f / 768.0f) - mean * mean;
  float inv = rsqrtf(var + 1e-5f);
  u16* outr = out + (size_t)row * DMODEL;
  outr[tid]       = f2b((v0 - mean) * inv * b2f(g[tid])       + b2f(b[tid]));
  outr[tid + 256] = f2b((v1 - mean) * inv * b2f(g[tid + 256]) + b2f(b[tid + 256]));
  outr[tid + 512] = f2b((v2 - mean) * inv * b2f(g[tid + 512]) + b2f(b[tid + 512]));
}

// ---------------- LayerNorm (f32 input) ----------------
__global__ __launch_bounds__(256) void ln_f32_kernel(
    const float* __restrict__ x, const u16* __restrict__ g,
    const u16* __restrict__ b, u16* __restrict__ out) {
  int row = blockIdx.x;
  int tid = threadIdx.x;
  const float* xr = x + (size_t)row * DMODEL;
  float v0 = xr[tid], v1 = xr[tid + 256], v2 = xr[tid + 512];
  float s = v0 + v1 + v2;
  float q = v0 * v0 + v1 * v1 + v2 * v2;
#pragma unroll
  for (int off = 32; off; off >>= 1) {
    s += __shfl_xor(s, off, 64);
    q += __shfl_xor(q, off, 64);
  }
  __shared__ float rs[4], rq[4];
  int wv = tid >> 6;
  if ((tid & 63) == 0) { rs[wv] = s; rq[wv] = q; }
  __syncthreads();
  s = rs[0] + rs[1] + rs[2] + rs[3];
  q = rq[0] + rq[1] + rq[2] + rq[3];
  float mean = s * (1.0f / 768.0f);
  float var = q * (1.0f / 768.0f) - mean * mean;
  float inv = rsqrtf(var + 1e-5f);
  u16* outr = out + (size_t)row * DMODEL;
  outr[tid]       = f2b((v0 - mean) * inv * b2f(g[tid])       + b2f(b[tid]));
  outr[tid + 256] = f2b((v1 - mean) * inv * b2f(g[tid + 256]) + b2f(b[tid + 256]));
  outr[tid + 512] = f2b((v2 - mean) * inv * b2f(g[tid + 512]) + b2f(b[tid + 512]));
}

// ---------------- MFMA GEMM: C = A[M,K] * W[N,K]^T + bias, bf16 out ----------
__global__ __launch_bounds__(256) void gemm_bt(
    const u16* __restrict__ Ap, const u16* __restrict__ Wp,
    const u16* __restrict__ bias, u16* __restrict__ Cp, int Nn, int K) {
  const __bf16* A = (const __bf16*)Ap;
  const __bf16* W = (const __bf16*)Wp;
  int lane = threadIdx.x & 63;
  int wv = threadIdx.x >> 6;
  int q16 = lane & 15, quad = lane >> 4;
  int mBase = blockIdx.y * 128 + (wv >> 1) * 64;
  int nBase = blockIdx.x * 128 + (wv & 1) * 64;
  f32x4 acc[4][4] = {};
  for (int k0 = 0; k0 < K; k0 += 32) {
    bf16x8 af[4], bfr[4];
#pragma unroll
    for (int si = 0; si < 4; ++si)
      af[si] = *(const bf16x8*)(A + (size_t)(mBase + si * 16 + q16) * K + k0 + quad * 8);
#pragma unroll
    for (int sj = 0; sj < 4; ++sj)
      bfr[sj] = *(const bf16x8*)(W + (size_t)(nBase + sj * 16 + q16) * K + k0 + quad * 8);
#pragma unroll
    for (int si = 0; si < 4; ++si)
#pragma unroll
      for (int sj = 0; sj < 4; ++sj)
        acc[si][sj] = __builtin_amdgcn_mfma_f32_16x16x32_bf16(af[si], bfr[sj], acc[si][sj], 0, 0, 0);
  }
#pragma unroll
  for (int si = 0; si < 4; ++si)
#pragma unroll
    for (int sj = 0; sj < 4; ++sj) {
      int col = nBase + sj * 16 + q16;
      float bcol = b2f(bias[col]);
#pragma unroll
      for (int r = 0; r < 4; ++r) {
        int rowi = mBase + si * 16 + quad * 4 + r;
        Cp[(size_t)rowi * Nn + col] = f2b(acc[si][sj][r] + bcol);
      }
    }
}

// ---------------- final MFMA GEMM: out(f32) = x1 + act @ wout^T + bias -------
__global__ __launch_bounds__(256) void gemm_out_f32(
    const u16* __restrict__ Ap, const u16* __restrict__ Wp,
    const u16* __restrict__ bias, const float* __restrict__ res,
    float* __restrict__ Cp, int Nn, int K) {
  const __bf16* A = (const __bf16*)Ap;
  const __bf16* W = (const __bf16*)Wp;
  int lane = threadIdx.x & 63;
  int wv = threadIdx.x >> 6;
  int q16 = lane & 15, quad = lane >> 4;
  int mBase = blockIdx.y * 128 + (wv >> 1) * 64;
  int nBase = blockIdx.x * 128 + (wv & 1) * 64;
  f32x4 acc[4][4] = {};
  for (int k0 = 0; k0 < K; k0 += 32) {
    bf16x8 af[4], bfr[4];
#pragma unroll
    for (int si = 0; si < 4; ++si)
      af[si] = *(const bf16x8*)(A + (size_t)(mBase + si * 16 + q16) * K + k0 + quad * 8);
#pragma unroll
    for (int sj = 0; sj < 4; ++sj)
      bfr[sj] = *(const bf16x8*)(W + (size_t)(nBase + sj * 16 + q16) * K + k0 + quad * 8);
#pragma unroll
    for (int si = 0; si < 4; ++si)
#pragma unroll
      for (int sj = 0; sj < 4; ++sj)
        acc[si][sj] = __builtin_amdgcn_mfma_f32_16x16x32_bf16(af[si], bfr[sj], acc[si][sj], 0, 0, 0);
  }
#pragma unroll
  for (int si = 0; si < 4; ++si)
#pragma unroll
    for (int sj = 0; sj < 4; ++sj) {
      int col = nBase + sj * 16 + q16;
      float bcol = b2f(bias[col]);
#pragma unroll
      for (int r = 0; r < 4; ++r) {
        int rowi = mBase + si * 16 + quad * 4 + r;
        Cp[(size_t)rowi * Nn + col] = acc[si][sj][r] + bcol + res[(size_t)rowi * Nn + col];
      }
    }
}

// ---------------- fused FFN-in: act = silu(h2 @ Wu^T + bu) * (h2 @ Wg^T + bg)
__global__ __launch_bounds__(256) void ffn_in_kernel(
    const u16* __restrict__ hp, const u16* __restrict__ Wp,
    const u16* __restrict__ bias, u16* __restrict__ actp) {
  const __bf16* A = (const __bf16*)hp;
  const __bf16* W = (const __bf16*)Wp;
  int lane = threadIdx.x & 63;
  int wv = threadIdx.x >> 6;
  int q16 = lane & 15, quad = lane >> 4;
  int mBase = blockIdx.y * 128 + (wv >> 1) * 64;
  int cBase = blockIdx.x * 64 + (wv & 1) * 32;
  f32x4 au[4][2] = {}, ag[4][2] = {};
  for (int k0 = 0; k0 < DMODEL; k0 += 32) {
    bf16x8 af[4], wu[2], wg[2];
#pragma unroll
    for (int si = 0; si < 4; ++si)
      af[si] = *(const bf16x8*)(A + (size_t)(mBase + si * 16 + q16) * DMODEL + k0 + quad * 8);
#pragma unroll
    for (int sj = 0; sj < 2; ++sj) {
      wu[sj] = *(const bf16x8*)(W + (size_t)(cBase + sj * 16 + q16) * DMODEL + k0 + quad * 8);
      wg[sj] = *(const bf16x8*)(W + (size_t)(HIDDIM + cBase + sj * 16 + q16) * DMODEL + k0 + quad * 8);
    }
#pragma unroll
    for (int si = 0; si < 4; ++si)
#pragma unroll
      for (int sj = 0; sj < 2; ++sj) {
        au[si][sj] = __builtin_amdgcn_mfma_f32_16x16x32_bf16(af[si], wu[sj], au[si][sj], 0, 0, 0);
        ag[si][sj] = __builtin_amdgcn_mfma_f32_16x16x32_bf16(af[si], wg[sj], ag[si][sj], 0, 0, 0);
      }
  }
#pragma unroll
  for (int si = 0; si < 4; ++si)
#pragma unroll
    for (int sj = 0; sj < 2; ++sj) {
      int col = cBase + sj * 16 + q16;
      float bu = b2f(bias[col]);
      float bg = b2f(bias[HIDDIM + col]);
#pragma unroll
      for (int r = 0; r < 4; ++r) {
        int rowi = mBase + si * 16 + quad * 4 + r;
        float u = au[si][sj][r] + bu;
        float g = ag[si][sj][r] + bg;
        float s = u / (1.0f + __expf(-u));
        actp[(size_t)rowi * HIDDIM + col] = f2b(s * g);
      }
    }
}

// ---------------- coord bias p2[b,h,n] = (coords.relw) * LOG2E ---------------
__global__ __launch_bounds__(256) void p_kernel(
    const u16* __restrict__ coords, const u16* __restrict__ relw,
    float* __restrict__ p) {
  const float LOG2E = 1.4426950408889634f;
  int idx = blockIdx.x * 256 + threadIdx.x;  // B*N = 4096
  float c0 = b2f(coords[idx * 3 + 0]);
  float c1 = b2f(coords[idx * 3 + 1]);
  float c2 = b2f(coords[idx * 3 + 2]);
  int b = idx >> 10, n = idx & 1023;
#pragma unroll
  for (int h = 0; h < NHEAD; ++h) {
    float w0 = b2f(relw[h * 3 + 0]), w1 = b2f(relw[h * 3 + 1]), w2 = b2f(relw[h * 3 + 2]);
    p[(size_t)(b * NHEAD + h) * NTOK + n] = (c0 * w0 + c1 * w1 + c2 * w2) * LOG2E;
  }
}

// ---------------- V transpose: Vt[b][h][d][n] = V[b][n][h][d] ----------------
__global__ __launch_bounds__(256) void vt_kernel(const u16* __restrict__ qkvp,
                                                 u16* __restrict__ vtp) {
  int blk = blockIdx.x;            // b*192 + h*16 + nt
  int b = blk / 192;
  int rem = blk % 192;
  int h = rem >> 4;
  int nt = rem & 15;
  int wv = threadIdx.x >> 6;
  int d = threadIdx.x & 63;
  int n0 = nt * 64 + wv * 16;
  const u16* src = qkvp + ((size_t)(b * NTOK) + n0) * LD3 + 2 * DMODEL + h * 64 + d;
  u16* dst = vtp + ((size_t)((b * NHEAD + h) * 64 + d)) * NTOK + n0;
#pragma unroll
  for (int c = 0; c < 2; ++c) {
    u16 buf[8] __attribute__((aligned(16)));
#pragma unroll
    for (int i = 0; i < 8; ++i) buf[i] = src[(size_t)(c * 8 + i) * LD3];
    *(uint4*)(dst + c * 8) = *(const uint4*)buf;
  }
}

// ---------------- flash attention (swapped QK^T, lane-local softmax) ---------
// 3072 waves: 4 batches x 12 heads x 64 query-tiles of 16.
// S^T = mfma(K,Q): lane (quad,q16) holds S[j0+4*quad+r][i0+q16] -> the whole
// row-softmax for query q16 is lane-local (+2 cross-quad shfls). p_i cancels
// in the row softmax; p2 is pre-scaled by LOG2E. PV runs swapped too:
// O^T = mfma(Vt, P) -> accO[ds][r] = O[i0+q16][ds*16+quad*4+r] -> float4 store.
__global__ __launch_bounds__(256) void attn_kernel(
    const u16* __restrict__ qkvp, const u16* __restrict__ vtp,
    const float* __restrict__ p2, const u16* __restrict__ xp,
    float* __restrict__ x1) {
  const __bf16* qb = (const __bf16*)qkvp;
  __shared__ __align__(16) u16 Pl[4][16][40];   // 80 B row stride: 16B-aligned b128 reads, ~2-way banks
  int lane = threadIdx.x & 63;
  int wv = threadIdx.x >> 6;
  int wave = blockIdx.x * 4 + wv;          // 0..3071
  int b = wave / 768;
  int rem = wave % 768;
  int h = rem >> 6;
  int i0 = (rem & 63) * 16;
  int q16 = lane & 15, quad = lane >> 4;

  const float scl2 = 0.125f * 1.4426950408889634f;

  // Q = B-operand (rows at q16)
  const __bf16* qrow = qb + ((size_t)(b * NTOK) + i0 + q16) * LD3 + h * 64;
  bf16x8 bq0 = *(const bf16x8*)(qrow + quad * 8);
  bf16x8 bq1 = *(const bf16x8*)(qrow + 32 + quad * 8);

  const __bf16* vtb = (const __bf16*)vtp + (size_t)((b * NHEAD + h) * 64) * NTOK;
  const float* prow = p2 + (size_t)(b * NHEAD + h) * NTOK;

  float mrun = -1e30f, lsum = 0.f;
  f32x4 accO[4] = {};

  for (int j0 = 0; j0 < NTOK; j0 += 32) {
    // K = A-operand (rows at q16)
    const __bf16* krow0 = qb + ((size_t)(b * NTOK) + j0 + q16) * LD3 + DMODEL + h * 64;
    const __bf16* krow1 = krow0 + (size_t)16 * LD3;
    bf16x8 ka00 = *(const bf16x8*)(krow0 + quad * 8);
    bf16x8 ka01 = *(const bf16x8*)(krow0 + 32 + quad * 8);
    bf16x8 ka10 = *(const bf16x8*)(krow1 + quad * 8);
    bf16x8 ka11 = *(const bf16x8*)(krow1 + 32 + quad * 8);
    f32x4 st0 = {}, st1 = {};
    st0 = __builtin_amdgcn_mfma_f32_16x16x32_bf16(ka00, bq0, st0, 0, 0, 0);
    st0 = __builtin_amdgcn_mfma_f32_16x16x32_bf16(ka01, bq1, st0, 0, 0, 0);
    st1 = __builtin_amdgcn_mfma_f32_16x16x32_bf16(ka10, bq0, st1, 0, 0, 0);
    st1 = __builtin_amdgcn_mfma_f32_16x16x32_bf16(ka11, bq1, st1, 0, 0, 0);

    // bias: scores^T - p_j  (p_i cancels in row softmax)
    f32x4 pjl = *(const f32x4*)(prow + j0 + 4 * quad);
    f32x4 pjh = *(const f32x4*)(prow + j0 + 16 + 4 * quad);
    float sl[4], sh[4];
#pragma unroll
    for (int r = 0; r < 4; ++r) {
      sl[r] = st0[r] * scl2 - pjl[r];
      sh[r] = st1[r] * scl2 - pjh[r];
    }
    // lane-local max (8 vals) + cross-quad reduce (2 shfls)
    float lm = fmaxf(fmaxf(fmaxf(sl[0], sl[1]), fmaxf(sl[2], sl[3])),
                     fmaxf(fmaxf(sh[0], sh[1]), fmaxf(sh[2], sh[3])));
    lm = fmaxf(lm, __shfl_xor(lm, 16, 64));
    lm = fmaxf(lm, __shfl_xor(lm, 32, 64));
    float mn = fmaxf(mrun, lm);
    float alpha = exp2f(mrun - mn);
    mrun = mn;
    float pl[4], ph[4];
#pragma unroll
    for (int r = 0; r < 4; ++r) {
      pl[r] = exp2f(sl[r] - mn);
      ph[r] = exp2f(sh[r] - mn);
    }
    float ts = (pl[0] + pl[1]) + (pl[2] + pl[3]) +
               (ph[0] + ph[1]) + (ph[2] + ph[3]);
    ts += __shfl_xor(ts, 16, 64);
    ts += __shfl_xor(ts, 32, 64);
    lsum = lsum * alpha + ts;

    // P rows to LDS: lane writes P[q16][4q..4q+3] and P[q16][16+4q..+3]
    bf16x4 w0 = {(__bf16)pl[0], (__bf16)pl[1], (__bf16)pl[2], (__bf16)pl[3]};
    bf16x4 w1 = {(__bf16)ph[0], (__bf16)ph[1], (__bf16)ph[2], (__bf16)ph[3]};
    *(bf16x4*)(&Pl[wv][q16][4 * quad]) = w0;
    *(bf16x4*)(&Pl[wv][q16][16 + 4 * quad]) = w1;
    // B-frag: P row q16, k-slice quad*8..+7 (wave-private, no barrier)
    bf16x8 ap = *(const bf16x8*)(&Pl[wv][q16][quad * 8]);

#pragma unroll
    for (int ds = 0; ds < 4; ++ds) {
      bf16x8 av = *(const bf16x8*)(vtb + (size_t)(ds * 16 + q16) * NTOK + j0 + quad * 8);
      f32x4 c = accO[ds];
#pragma unroll
      for (int r = 0; r < 4; ++r) c[r] *= alpha;
      accO[ds] = __builtin_amdgcn_mfma_f32_16x16x32_bf16(av, ap, c, 0, 0, 0);
    }
  }

  float rl = 1.0f / lsum;
  size_t rowbase = ((size_t)(b * NTOK) + i0 + q16) * DMODEL + h * 64;
#pragma unroll
  for (int ds = 0; ds < 4; ++ds) {
    int d0 = ds * 16 + quad * 4;
    u16x4 xv = *(const u16x4*)(xp + rowbase + d0);
    f32x4 ov;
#pragma unroll
    for (int r = 0; r < 4; ++r) ov[r] = b2f(xv[r]) + accO[ds][r] * rl;
    *(f32x4*)(x1 + rowbase + d0) = ov;
  }
}

extern "C" void kernel_launch(void* const* d_in, const int* in_sizes, int n_in,
                              void* d_out, int out_size, void* d_ws, size_t ws_size,
                              hipStream_t stream) {
  // ---- host-side boundary tripwires (verified passing in R6) ----
  static const int esz[13] = {3145728, 12288, 768, 768, 1769472, 2304, 36,
                              768, 768, 3145728, 4096, 1572864, 768};
  float sig = -1.f;
  if (n_in != 13) {
    sig = 6000.f + 100.f * (float)n_in;
  } else {
    for (int i = 0; i < 13; ++i)
      if (in_sizes[i] != esz[i]) { sig = 1000.f + 100.f * (float)i; break; }
  }
  if (sig < 0.f && ws_size < 57258496ULL) sig = 3000.f;
  if (sig < 0.f && out_size != 3145728) sig = 3100.f;
  if (sig >= 0.f) {
    signal_kernel<<<(out_size + 255) / 256, 256, 0, stream>>>((float*)d_out, out_size, sig);
    return;
  }

  char* ws = (char*)d_ws;
  int*  flag    = (int*)ws;                       // 256 B
  u16*  cx      = (u16*)(ws + 256);               // 6291456
  u16*  cqkvw   = (u16*)(ws + 6291712);           // 3538944
  u16*  cwinw   = (u16*)(ws + 9830656);           // 6291456
  u16*  cwoutw  = (u16*)(ws + 16122112);          // 3145728
  u16*  ccoords = (u16*)(ws + 19267840);          // 24576
  u16*  cln1g   = (u16*)(ws + 19292416);          // 1536
  u16*  cln1b   = (u16*)(ws + 19293952);          // 1536
  u16*  cqkvb   = (u16*)(ws + 19295488);          // 4608
  u16*  crelw   = (u16*)(ws + 19300096);          // 72 (padded)
  u16*  cln2g   = (u16*)(ws + 19300352);          // 1536
  u16*  cln2b   = (u16*)(ws + 19301888);          // 1536
  u16*  cwinb   = (u16*)(ws + 19303424);          // 8192
  u16*  cwoutb  = (u16*)(ws + 19311616);          // 1536
  u16*  h       = (u16*)(ws + 19313152);          // 6291456 (LN out; dead between
                                                  //  gemm_bt and ln2 -> reused as Vt)
  u16*  qkv     = (u16*)(ws + 25604608);          // 18874368 (reused as act)
  float* pbuf   = (float*)(ws + 44478976);        // 196608
  float* x1     = (float*)(ws + 44675584);        // 12582912 -> end 57258496
  u16*  act     = qkv;
  u16*  vt      = h;   // Vt needs 4*12*64*1024*2 = 6291456 B == sizeof(h)

  // 0a. dtype flag (f32 confirmed; adaptive kept as insurance)
  detect_kernel<<<1, 256, 0, stream>>>((const u16*)d_in[0], flag);

  // 0b. canonicalize all 13 inputs to bf16 (linear C-order)
  CanonJobs jobs;
  u16* dsts[13] = {cx, ccoords, cln1g, cln1b, cqkvw, cqkvb, crelw,
                   cln2g, cln2b, cwinw, cwinb, cwoutw, cwoutb};
  for (int i = 0; i < 13; ++i) {
    jobs.s[i] = d_in[i];
    jobs.d[i] = dsts[i];
    jobs.n[i] = in_sizes[i];
  }
  canon_kernel<<<dim3(3072, 13), 256, 0, stream>>>(jobs, flag);

  // 1. h = LN1(x)
  ln_bf16_kernel<<<4096, 256, 0, stream>>>(cx, cln1g, cln1b, h);
  // 2. qkv = h @ qkv_w^T + qkv_b   (M=4096, N=2304, K=768)
  gemm_bt<<<dim3(18, 32), 256, 0, stream>>>(h, cqkvw, cqkvb, qkv, 2304, 768);
  // 3. p2[b,h,n] (pre-scaled by LOG2E)
  p_kernel<<<16, 256, 0, stream>>>(ccoords, crelw, pbuf);
  // 3b. Vt[b][h][d][n] = V  (h buffer is dead here; gemm_bt already consumed it)
  vt_kernel<<<768, 256, 0, stream>>>(qkv, vt);
  // 4. x1 = x + attention(qkv, Vt, p2)   (3072 waves / 768 blocks)
  attn_kernel<<<768, 256, 0, stream>>>(qkv, vt, pbuf, cx, x1);
  // 5. h2 = LN2(x1)  (reuse h)
  ln_f32_kernel<<<4096, 256, 0, stream>>>(x1, cln2g, cln2b, h);
  // 6+7. act = silu(h2 @ Wu^T + bu) * (h2 @ Wg^T + bg)   (fused)
  ffn_in_kernel<<<dim3(32, 32), 256, 0, stream>>>(h, cwinw, cwinb, act);
  // 8. out(F32) = x1 + act @ wout_w^T + wout_b   (M=4096, N=768, K=2048)
  gemm_out_f32<<<dim3(6, 32), 256, 0, stream>>>(act, cwoutw, cwoutb, x1, (float*)d_out, 768, 2048);
}

// Round 4
// 349.154 us; speedup vs baseline: 1.2995x; 1.2995x over previous
//
#include <hip/hip_runtime.h>
#include <math.h>

typedef unsigned short u16;
typedef __bf16 bf16x8 __attribute__((ext_vector_type(8)));
typedef __bf16 bf16x4 __attribute__((ext_vector_type(4)));
typedef u16 u16x4 __attribute__((ext_vector_type(4)));
typedef float f32x4 __attribute__((ext_vector_type(4)));

// ---- constants ----
// B=4, N=1024, D=768, H=12, Dh=64, HID=2048, 3D=2304
#define NTOK 1024
#define DMODEL 768
#define NHEAD 12
#define LD3 2304
#define HIDDIM 2048

__device__ __forceinline__ float b2f(u16 u) {
  unsigned int t = ((unsigned int)u) << 16;
  float f;
  __builtin_memcpy(&f, &t, 4);
  return f;
}
__device__ __forceinline__ u16 f2b(float f) {
  unsigned int t;
  __builtin_memcpy(&t, &f, 4);
  t += 0x7fffu + ((t >> 16) & 1u);
  return (u16)(t >> 16);
}

// async global->LDS, 16B per lane; LDS dest is wave-uniform base + lane*16
__device__ __forceinline__ void gl_lds16(const u16* g, u16* l) {
  __builtin_amdgcn_global_load_lds(
      (__attribute__((address_space(1))) const unsigned int*)g,
      (__attribute__((address_space(3))) unsigned int*)l, 16, 0, 0);
}

// ---------------- host-assert signal (f32 output now) ------------------------
__global__ __launch_bounds__(256) void signal_kernel(float* __restrict__ out,
                                                     int n, float c) {
  int i = blockIdx.x * 256 + threadIdx.x;
  if (i < n) out[i] = c;
}

// ---------------- input dtype detection (verified f32: flag=1, R6) -----------
__global__ __launch_bounds__(256) void detect_kernel(const u16* __restrict__ x,
                                                     int* __restrict__ flag) {
  __shared__ int cnt;
  if (threadIdx.x == 0) cnt = 0;
  __syncthreads();
  int bad = 0;
  for (int i = threadIdx.x; i < 4096; i += 256) {
    u16 v = x[2 * i];
    int e = (v >> 7) & 0xFF;
    if (e >= 0xC0) bad++;
  }
  atomicAdd(&cnt, bad);
  __syncthreads();
  if (threadIdx.x == 0) *flag = (cnt >= 64) ? 1 : 0;
}

// ---------------- canonicalize all inputs to bf16 (linear, C-order) ----------
struct CanonJobs {
  const void* s[13];
  u16* d[13];
  int n[13];
};

__global__ __launch_bounds__(256) void canon_kernel(CanonJobs jobs,
                                                    const int* __restrict__ flag) {
  int j = blockIdx.y;
  int n = jobs.n[j];
  const void* s = jobs.s[j];
  u16* d = jobs.d[j];
  bool isf32 = (*flag != 0);
  for (int i = blockIdx.x * 256 + threadIdx.x; i < n; i += gridDim.x * 256) {
    d[i] = isf32 ? f2b(((const float*)s)[i]) : ((const u16*)s)[i];
  }
}

// ---------------- LayerNorm (bf16 input) ----------------
__global__ __launch_bounds__(256) void ln_bf16_kernel(
    const u16* __restrict__ x, const u16* __restrict__ g,
    const u16* __restrict__ b, u16* __restrict__ out) {
  int row = blockIdx.x;
  int tid = threadIdx.x;
  const u16* xr = x + (size_t)row * DMODEL;
  float v0 = b2f(xr[tid]), v1 = b2f(xr[tid + 256]), v2 = b2f(xr[tid + 512]);
  float s = v0 + v1 + v2;
  float q = v0 * v0 + v1 * v1 + v2 * v2;
#pragma unroll
  for (int off = 32; off; off >>= 1) {
    s += __shfl_xor(s, off, 64);
    q += __shfl_xor(q, off, 64);
  }
  __shared__ float rs[4], rq[4];
  int wv = tid >> 6;
  if ((tid & 63) == 0) { rs[wv] = s; rq[wv] = q; }
  __syncthreads();
  s = rs[0] + rs[1] + rs[2] + rs[3];
  q = rq[0] + rq[1] + rq[2] + rq[3];
  float mean = s * (1.0f / 768.0f);
  float var = q * (1.0f / 768.0f) - mean * mean;
  float inv = rsqrtf(var + 1e-5f);
  u16* outr = out + (size_t)row * DMODEL;
  outr[tid]       = f2b((v0 - mean) * inv * b2f(g[tid])       + b2f(b[tid]));
  outr[tid + 256] = f2b((v1 - mean) * inv * b2f(g[tid + 256]) + b2f(b[tid + 256]));
  outr[tid + 512] = f2b((v2 - mean) * inv * b2f(g[tid + 512]) + b2f(b[tid + 512]));
}

// ---------------- LayerNorm (f32 input) ----------------
__global__ __launch_bounds__(256) void ln_f32_kernel(
    const float* __restrict__ x, const u16* __restrict__ g,
    const u16* __restrict__ b, u16* __restrict__ out) {
  int row = blockIdx.x;
  int tid = threadIdx.x;
  const float* xr = x + (size_t)row * DMODEL;
  float v0 = xr[tid], v1 = xr[tid + 256], v2 = xr[tid + 512];
  float s = v0 + v1 + v2;
  float q = v0 * v0 + v1 * v1 + v2 * v2;
#pragma unroll
  for (int off = 32; off; off >>= 1) {
    s += __shfl_xor(s, off, 64);
    q += __shfl_xor(q, off, 64);
  }
  __shared__ float rs[4], rq[4];
  int wv = tid >> 6;
  if ((tid & 63) == 0) { rs[wv] = s; rq[wv] = q; }
  __syncthreads();
  s = rs[0] + rs[1] + rs[2] + rs[3];
  q = rq[0] + rq[1] + rq[2] + rq[3];
  float mean = s * (1.0f / 768.0f);
  float var = q * (1.0f / 768.0f) - mean * mean;
  float inv = rsqrtf(var + 1e-5f);
  u16* outr = out + (size_t)row * DMODEL;
  outr[tid]       = f2b((v0 - mean) * inv * b2f(g[tid])       + b2f(b[tid]));
  outr[tid + 256] = f2b((v1 - mean) * inv * b2f(g[tid + 256]) + b2f(b[tid + 256]));
  outr[tid + 512] = f2b((v2 - mean) * inv * b2f(g[tid + 512]) + b2f(b[tid + 512]));
}

// ====== shared LDS-staged 128x128 mainloop (m97 structure) ======
// Block = 256 thr = 4 waves (2m x 2n), wave tile 64x64 (4x4 16x16x32 frags).
// Per K-step: stage A[128][32] + B[128][32] into linear LDS via
// global_load_lds (8 chunks of 1KB each, 2 chunks/wave/matrix), barrier,
// ds_read_b128 fragments, 16 MFMA/wave, barrier.
__device__ __forceinline__ void gemm128_mainloop(
    const u16* __restrict__ A, const u16* __restrict__ W, int K,
    int mB0, int nB0, u16* Al, u16* Bl, f32x4 (&acc)[4][4]) {
  int lane = threadIdx.x & 63;
  int wv = threadIdx.x >> 6;
  int q16 = lane & 15, quad = lane >> 4;
  int mW = (wv >> 1) * 64, nW = (wv & 1) * 64;
  int srow = lane >> 2, scol = (lane & 3) * 8;
  for (int k0 = 0; k0 < K; k0 += 32) {
#pragma unroll
    for (int c = 0; c < 2; ++c) {
      int ch = wv * 2 + c;
      int r = ch * 16 + srow;
      gl_lds16(A + (size_t)(mB0 + r) * K + k0 + scol, Al + ch * 512);
      gl_lds16(W + (size_t)(nB0 + r) * K + k0 + scol, Bl + ch * 512);
    }
    __syncthreads();
    bf16x8 af[4], bfr[4];
#pragma unroll
    for (int si = 0; si < 4; ++si)
      af[si] = *(const bf16x8*)((const __bf16*)Al + (mW + si * 16 + q16) * 32 + quad * 8);
#pragma unroll
    for (int sj = 0; sj < 4; ++sj)
      bfr[sj] = *(const bf16x8*)((const __bf16*)Bl + (nW + sj * 16 + q16) * 32 + quad * 8);
#pragma unroll
    for (int si = 0; si < 4; ++si)
#pragma unroll
      for (int sj = 0; sj < 4; ++sj)
        acc[si][sj] = __builtin_amdgcn_mfma_f32_16x16x32_bf16(af[si], bfr[sj], acc[si][sj], 0, 0, 0);
    __syncthreads();
  }
}

// ---------------- MFMA GEMM: C = A[M,K] * W[N,K]^T + bias, bf16 out ----------
__global__ __launch_bounds__(256) void gemm_bt(
    const u16* __restrict__ Ap, const u16* __restrict__ Wp,
    const u16* __restrict__ bias, u16* __restrict__ Cp, int Nn, int K) {
  __shared__ __align__(16) u16 Al[128 * 32], Bl[128 * 32];
  int lane = threadIdx.x & 63;
  int wv = threadIdx.x >> 6;
  int q16 = lane & 15, quad = lane >> 4;
  int mBase = blockIdx.y * 128 + (wv >> 1) * 64;
  int nBase = blockIdx.x * 128 + (wv & 1) * 64;
  f32x4 acc[4][4] = {};
  gemm128_mainloop(Ap, Wp, K, blockIdx.y * 128, blockIdx.x * 128, Al, Bl, acc);
#pragma unroll
  for (int si = 0; si < 4; ++si)
#pragma unroll
    for (int sj = 0; sj < 4; ++sj) {
      int col = nBase + sj * 16 + q16;
      float bcol = b2f(bias[col]);
#pragma unroll
      for (int r = 0; r < 4; ++r) {
        int rowi = mBase + si * 16 + quad * 4 + r;
        Cp[(size_t)rowi * Nn + col] = f2b(acc[si][sj][r] + bcol);
      }
    }
}

// ---------------- final MFMA GEMM: out(f32) = x1 + act @ wout^T + bias -------
__global__ __launch_bounds__(256) void gemm_out_f32(
    const u16* __restrict__ Ap, const u16* __restrict__ Wp,
    const u16* __restrict__ bias, const float* __restrict__ res,
    float* __restrict__ Cp, int Nn, int K) {
  __shared__ __align__(16) u16 Al[128 * 32], Bl[128 * 32];
  int lane = threadIdx.x & 63;
  int wv = threadIdx.x >> 6;
  int q16 = lane & 15, quad = lane >> 4;
  int mBase = blockIdx.y * 128 + (wv >> 1) * 64;
  int nBase = blockIdx.x * 128 + (wv & 1) * 64;
  f32x4 acc[4][4] = {};
  gemm128_mainloop(Ap, Wp, K, blockIdx.y * 128, blockIdx.x * 128, Al, Bl, acc);
#pragma unroll
  for (int si = 0; si < 4; ++si)
#pragma unroll
    for (int sj = 0; sj < 4; ++sj) {
      int col = nBase + sj * 16 + q16;
      float bcol = b2f(bias[col]);
#pragma unroll
      for (int r = 0; r < 4; ++r) {
        int rowi = mBase + si * 16 + quad * 4 + r;
        Cp[(size_t)rowi * Nn + col] = acc[si][sj][r] + bcol + res[(size_t)rowi * Nn + col];
      }
    }
}

// ---------------- fused FFN-in: act = silu(h2 @ Wu^T + bu) * (h2 @ Wg^T + bg)
// Block covers 128 m-rows x 64 act-cols; B-tile stacks 64 Wu rows + 64 Wg rows.
__global__ __launch_bounds__(256) void ffn_in_kernel(
    const u16* __restrict__ hp, const u16* __restrict__ Wp,
    const u16* __restrict__ bias, u16* __restrict__ actp) {
  __shared__ __align__(16) u16 Al[128 * 32], Bl[128 * 32];
  int lane = threadIdx.x & 63;
  int wv = threadIdx.x >> 6;
  int q16 = lane & 15, quad = lane >> 4;
  int mB0 = blockIdx.y * 128;
  int cB0 = blockIdx.x * 64;
  int mW = (wv >> 1) * 64;
  int cW = (wv & 1) * 32;
  int srow = lane >> 2, scol = (lane & 3) * 8;
  f32x4 au[4][2] = {}, ag[4][2] = {};
  for (int k0 = 0; k0 < DMODEL; k0 += 32) {
#pragma unroll
    for (int c = 0; c < 2; ++c) {
      int ch = wv * 2 + c;
      int r = ch * 16 + srow;
      gl_lds16(hp + (size_t)(mB0 + r) * DMODEL + k0 + scol, Al + ch * 512);
      int grow = (r < 64) ? (cB0 + r) : (HIDDIM + cB0 + r - 64);
      gl_lds16(Wp + (size_t)grow * DMODEL + k0 + scol, Bl + ch * 512);
    }
    __syncthreads();
    bf16x8 af[4], wu[2], wg[2];
#pragma unroll
    for (int si = 0; si < 4; ++si)
      af[si] = *(const bf16x8*)((const __bf16*)Al + (mW + si * 16 + q16) * 32 + quad * 8);
#pragma unroll
    for (int sj = 0; sj < 2; ++sj) {
      wu[sj] = *(const bf16x8*)((const __bf16*)Bl + (cW + sj * 16 + q16) * 32 + quad * 8);
      wg[sj] = *(const bf16x8*)((const __bf16*)Bl + (64 + cW + sj * 16 + q16) * 32 + quad * 8);
    }
#pragma unroll
    for (int si = 0; si < 4; ++si)
#pragma unroll
      for (int sj = 0; sj < 2; ++sj) {
        au[si][sj] = __builtin_amdgcn_mfma_f32_16x16x32_bf16(af[si], wu[sj], au[si][sj], 0, 0, 0);
        ag[si][sj] = __builtin_amdgcn_mfma_f32_16x16x32_bf16(af[si], wg[sj], ag[si][sj], 0, 0, 0);
      }
    __syncthreads();
  }
#pragma unroll
  for (int si = 0; si < 4; ++si)
#pragma unroll
    for (int sj = 0; sj < 2; ++sj) {
      int col = cB0 + cW + sj * 16 + q16;
      float bu = b2f(bias[col]);
      float bg = b2f(bias[HIDDIM + col]);
#pragma unroll
      for (int r = 0; r < 4; ++r) {
        int rowi = mB0 + mW + si * 16 + quad * 4 + r;
        float u = au[si][sj][r] + bu;
        float g = ag[si][sj][r] + bg;
        float s = u / (1.0f + __expf(-u));
        actp[(size_t)rowi * HIDDIM + col] = f2b(s * g);
      }
    }
}

// ---------------- coord bias p2[b,h,n] = (coords.relw) * LOG2E ---------------
__global__ __launch_bounds__(256) void p_kernel(
    const u16* __restrict__ coords, const u16* __restrict__ relw,
    float* __restrict__ p) {
  const float LOG2E = 1.4426950408889634f;
  int idx = blockIdx.x * 256 + threadIdx.x;  // B*N = 4096
  float c0 = b2f(coords[idx * 3 + 0]);
  float c1 = b2f(coords[idx * 3 + 1]);
  float c2 = b2f(coords[idx * 3 + 2]);
  int b = idx >> 10, n = idx & 1023;
#pragma unroll
  for (int h = 0; h < NHEAD; ++h) {
    float w0 = b2f(relw[h * 3 + 0]), w1 = b2f(relw[h * 3 + 1]), w2 = b2f(relw[h * 3 + 2]);
    p[(size_t)(b * NHEAD + h) * NTOK + n] = (c0 * w0 + c1 * w1 + c2 * w2) * LOG2E;
  }
}

// ---------------- V transpose: Vt[b][h][d][n] = V[b][n][h][d] ----------------
__global__ __launch_bounds__(256) void vt_kernel(const u16* __restrict__ qkvp,
                                                 u16* __restrict__ vtp) {
  int blk = blockIdx.x;            // b*192 + h*16 + nt
  int b = blk / 192;
  int rem = blk % 192;
  int h = rem >> 4;
  int nt = rem & 15;
  int wv = threadIdx.x >> 6;
  int d = threadIdx.x & 63;
  int n0 = nt * 64 + wv * 16;
  const u16* src = qkvp + ((size_t)(b * NTOK) + n0) * LD3 + 2 * DMODEL + h * 64 + d;
  u16* dst = vtp + ((size_t)((b * NHEAD + h) * 64 + d)) * NTOK + n0;
#pragma unroll
  for (int c = 0; c < 2; ++c) {
    u16 buf[8] __attribute__((aligned(16)));
#pragma unroll
    for (int i = 0; i < 8; ++i) buf[i] = src[(size_t)(c * 8 + i) * LD3];
    *(uint4*)(dst + c * 8) = *(const uint4*)buf;
  }
}

// ---------------- flash attention (swapped QK^T, lane-local softmax) ---------
__global__ __launch_bounds__(256) void attn_kernel(
    const u16* __restrict__ qkvp, const u16* __restrict__ vtp,
    const float* __restrict__ p2, const u16* __restrict__ xp,
    float* __restrict__ x1) {
  const __bf16* qb = (const __bf16*)qkvp;
  __shared__ __align__(16) u16 Pl[4][16][40];   // 80 B row stride
  int lane = threadIdx.x & 63;
  int wv = threadIdx.x >> 6;
  int wave = blockIdx.x * 4 + wv;          // 0..3071
  int b = wave / 768;
  int rem = wave % 768;
  int h = rem >> 6;
  int i0 = (rem & 63) * 16;
  int q16 = lane & 15, quad = lane >> 4;

  const float scl2 = 0.125f * 1.4426950408889634f;

  const __bf16* qrow = qb + ((size_t)(b * NTOK) + i0 + q16) * LD3 + h * 64;
  bf16x8 bq0 = *(const bf16x8*)(qrow + quad * 8);
  bf16x8 bq1 = *(const bf16x8*)(qrow + 32 + quad * 8);

  const __bf16* vtb = (const __bf16*)vtp + (size_t)((b * NHEAD + h) * 64) * NTOK;
  const float* prow = p2 + (size_t)(b * NHEAD + h) * NTOK;

  float mrun = -1e30f, lsum = 0.f;
  f32x4 accO[4] = {};

  for (int j0 = 0; j0 < NTOK; j0 += 32) {
    const __bf16* krow0 = qb + ((size_t)(b * NTOK) + j0 + q16) * LD3 + DMODEL + h * 64;
    const __bf16* krow1 = krow0 + (size_t)16 * LD3;
    bf16x8 ka00 = *(const bf16x8*)(krow0 + quad * 8);
    bf16x8 ka01 = *(const bf16x8*)(krow0 + 32 + quad * 8);
    bf16x8 ka10 = *(const bf16x8*)(krow1 + quad * 8);
    bf16x8 ka11 = *(const bf16x8*)(krow1 + 32 + quad * 8);
    f32x4 st0 = {}, st1 = {};
    st0 = __builtin_amdgcn_mfma_f32_16x16x32_bf16(ka00, bq0, st0, 0, 0, 0);
    st0 = __builtin_amdgcn_mfma_f32_16x16x32_bf16(ka01, bq1, st0, 0, 0, 0);
    st1 = __builtin_amdgcn_mfma_f32_16x16x32_bf16(ka10, bq0, st1, 0, 0, 0);
    st1 = __builtin_amdgcn_mfma_f32_16x16x32_bf16(ka11, bq1, st1, 0, 0, 0);

    f32x4 pjl = *(const f32x4*)(prow + j0 + 4 * quad);
    f32x4 pjh = *(const f32x4*)(prow + j0 + 16 + 4 * quad);
    float sl[4], sh[4];
#pragma unroll
    for (int r = 0; r < 4; ++r) {
      sl[r] = st0[r] * scl2 - pjl[r];
      sh[r] = st1[r] * scl2 - pjh[r];
    }
    float lm = fmaxf(fmaxf(fmaxf(sl[0], sl[1]), fmaxf(sl[2], sl[3])),
                     fmaxf(fmaxf(sh[0], sh[1]), fmaxf(sh[2], sh[3])));
    lm = fmaxf(lm, __shfl_xor(lm, 16, 64));
    lm = fmaxf(lm, __shfl_xor(lm, 32, 64));
    float mn = fmaxf(mrun, lm);
    float alpha = exp2f(mrun - mn);
    mrun = mn;
    float pl[4], ph[4];
#pragma unroll
    for (int r = 0; r < 4; ++r) {
      pl[r] = exp2f(sl[r] - mn);
      ph[r] = exp2f(sh[r] - mn);
    }
    float ts = (pl[0] + pl[1]) + (pl[2] + pl[3]) +
               (ph[0] + ph[1]) + (ph[2] + ph[3]);
    ts += __shfl_xor(ts, 16, 64);
    ts += __shfl_xor(ts, 32, 64);
    lsum = lsum * alpha + ts;

    bf16x4 w0 = {(__bf16)pl[0], (__bf16)pl[1], (__bf16)pl[2], (__bf16)pl[3]};
    bf16x4 w1 = {(__bf16)ph[0], (__bf16)ph[1], (__bf16)ph[2], (__bf16)ph[3]};
    *(bf16x4*)(&Pl[wv][q16][4 * quad]) = w0;
    *(bf16x4*)(&Pl[wv][q16][16 + 4 * quad]) = w1;
    bf16x8 ap = *(const bf16x8*)(&Pl[wv][q16][quad * 8]);

#pragma unroll
    for (int ds = 0; ds < 4; ++ds) {
      bf16x8 av = *(const bf16x8*)(vtb + (size_t)(ds * 16 + q16) * NTOK + j0 + quad * 8);
      f32x4 c = accO[ds];
#pragma unroll
      for (int r = 0; r < 4; ++r) c[r] *= alpha;
      accO[ds] = __builtin_amdgcn_mfma_f32_16x16x32_bf16(av, ap, c, 0, 0, 0);
    }
  }

  float rl = 1.0f / lsum;
  size_t rowbase = ((size_t)(b * NTOK) + i0 + q16) * DMODEL + h * 64;
#pragma unroll
  for (int ds = 0; ds < 4; ++ds) {
    int d0 = ds * 16 + quad * 4;
    u16x4 xv = *(const u16x4*)(xp + rowbase + d0);
    f32x4 ov;
#pragma unroll
    for (int r = 0; r < 4; ++r) ov[r] = b2f(xv[r]) + accO[ds][r] * rl;
    *(f32x4*)(x1 + rowbase + d0) = ov;
  }
}

extern "C" void kernel_launch(void* const* d_in, const int* in_sizes, int n_in,
                              void* d_out, int out_size, void* d_ws, size_t ws_size,
                              hipStream_t stream) {
  // ---- host-side boundary tripwires (verified passing in R6) ----
  static const int esz[13] = {3145728, 12288, 768, 768, 1769472, 2304, 36,
                              768, 768, 3145728, 4096, 1572864, 768};
  float sig = -1.f;
  if (n_in != 13) {
    sig = 6000.f + 100.f * (float)n_in;
  } else {
    for (int i = 0; i < 13; ++i)
      if (in_sizes[i] != esz[i]) { sig = 1000.f + 100.f * (float)i; break; }
  }
  if (sig < 0.f && ws_size < 57258496ULL) sig = 3000.f;
  if (sig < 0.f && out_size != 3145728) sig = 3100.f;
  if (sig >= 0.f) {
    signal_kernel<<<(out_size + 255) / 256, 256, 0, stream>>>((float*)d_out, out_size, sig);
    return;
  }

  char* ws = (char*)d_ws;
  int*  flag    = (int*)ws;                       // 256 B
  u16*  cx      = (u16*)(ws + 256);               // 6291456
  u16*  cqkvw   = (u16*)(ws + 6291712);           // 3538944
  u16*  cwinw   = (u16*)(ws + 9830656);           // 6291456
  u16*  cwoutw  = (u16*)(ws + 16122112);          // 3145728
  u16*  ccoords = (u16*)(ws + 19267840);          // 24576
  u16*  cln1g   = (u16*)(ws + 19292416);          // 1536
  u16*  cln1b   = (u16*)(ws + 19293952);          // 1536
  u16*  cqkvb   = (u16*)(ws + 19295488);          // 4608
  u16*  crelw   = (u16*)(ws + 19300096);          // 72 (padded)
  u16*  cln2g   = (u16*)(ws + 19300352);          // 1536
  u16*  cln2b   = (u16*)(ws + 19301888);          // 1536
  u16*  cwinb   = (u16*)(ws + 19303424);          // 8192
  u16*  cwoutb  = (u16*)(ws + 19311616);          // 1536
  u16*  h       = (u16*)(ws + 19313152);          // 6291456 (LN out; dead between
                                                  //  gemm_bt and ln2 -> reused as Vt)
  u16*  qkv     = (u16*)(ws + 25604608);          // 18874368 (reused as act)
  float* pbuf   = (float*)(ws + 44478976);        // 196608
  float* x1     = (float*)(ws + 44675584);        // 12582912 -> end 57258496
  u16*  act     = qkv;
  u16*  vt      = h;   // Vt needs 4*12*64*1024*2 = 6291456 B == sizeof(h)

  // 0a. dtype flag (f32 confirmed; adaptive kept as insurance)
  detect_kernel<<<1, 256, 0, stream>>>((const u16*)d_in[0], flag);

  // 0b. canonicalize all 13 inputs to bf16 (linear C-order)
  CanonJobs jobs;
  u16* dsts[13] = {cx, ccoords, cln1g, cln1b, cqkvw, cqkvb, crelw,
                   cln2g, cln2b, cwinw, cwinb, cwoutw, cwoutb};
  for (int i = 0; i < 13; ++i) {
    jobs.s[i] = d_in[i];
    jobs.d[i] = dsts[i];
    jobs.n[i] = in_sizes[i];
  }
  canon_kernel<<<dim3(3072, 13), 256, 0, stream>>>(jobs, flag);

  // 1. h = LN1(x)
  ln_bf16_kernel<<<4096, 256, 0, stream>>>(cx, cln1g, cln1b, h);
  // 2. qkv = h @ qkv_w^T + qkv_b   (M=4096, N=2304, K=768)
  gemm_bt<<<dim3(18, 32), 256, 0, stream>>>(h, cqkvw, cqkvb, qkv, 2304, 768);
  // 3. p2[b,h,n] (pre-scaled by LOG2E)
  p_kernel<<<16, 256, 0, stream>>>(ccoords, crelw, pbuf);
  // 3b. Vt[b][h][d][n] = V  (h buffer is dead here; gemm_bt already consumed it)
  vt_kernel<<<768, 256, 0, stream>>>(qkv, vt);
  // 4. x1 = x + attention(qkv, Vt, p2)   (3072 waves / 768 blocks)
  attn_kernel<<<768, 256, 0, stream>>>(qkv, vt, pbuf, cx, x1);
  // 5. h2 = LN2(x1)  (reuse h)
  ln_f32_kernel<<<4096, 256, 0, stream>>>(x1, cln2g, cln2b, h);
  // 6+7. act = silu(h2 @ Wu^T + bu) * (h2 @ Wg^T + bg)   (fused, LDS-staged)
  ffn_in_kernel<<<dim3(32, 32), 256, 0, stream>>>(h, cwinw, cwinb, act);
  // 8. out(F32) = x1 + act @ wout_w^T + wout_b   (M=4096, N=768, K=2048)
  gemm_out_f32<<<dim3(6, 32), 256, 0, stream>>>(act, cwoutw, cwoutb, x1, (float*)d_out, 768, 2048);
}

// Round 5
// 303.132 us; speedup vs baseline: 1.4968x; 1.1518x over previous
//
#include <hip/hip_runtime.h>
#include <math.h>

typedef unsigned short u16;
typedef __bf16 bf16x8 __attribute__((ext_vector_type(8)));
typedef __bf16 bf16x4 __attribute__((ext_vector_type(4)));
typedef u16 u16x4 __attribute__((ext_vector_type(4)));
typedef float f32x4 __attribute__((ext_vector_type(4)));

// ---- constants ----
// B=4, N=1024, D=768, H=12, Dh=64, HID=2048, 3D=2304
#define NTOK 1024
#define DMODEL 768
#define NHEAD 12
#define LD3 2304
#define HIDDIM 2048

__device__ __forceinline__ float b2f(u16 u) {
  unsigned int t = ((unsigned int)u) << 16;
  float f;
  __builtin_memcpy(&f, &t, 4);
  return f;
}
__device__ __forceinline__ u16 f2b(float f) {
  unsigned int t;
  __builtin_memcpy(&t, &f, 4);
  t += 0x7fffu + ((t >> 16) & 1u);
  return (u16)(t >> 16);
}

// async global->LDS, 16B per lane; LDS dest is wave-uniform base + lane*16
__device__ __forceinline__ void gl_lds16(const u16* g, u16* l) {
  __builtin_amdgcn_global_load_lds(
      (__attribute__((address_space(1))) const unsigned int*)g,
      (__attribute__((address_space(3))) unsigned int*)l, 16, 0, 0);
}

// ---------------- host-assert signal (f32 output now) ------------------------
__global__ __launch_bounds__(256) void signal_kernel(float* __restrict__ out,
                                                     int n, float c) {
  int i = blockIdx.x * 256 + threadIdx.x;
  if (i < n) out[i] = c;
}

// ---------------- input dtype detection (verified f32: flag=1, R6) -----------
__global__ __launch_bounds__(256) void detect_kernel(const u16* __restrict__ x,
                                                     int* __restrict__ flag) {
  __shared__ int cnt;
  if (threadIdx.x == 0) cnt = 0;
  __syncthreads();
  int bad = 0;
  for (int i = threadIdx.x; i < 4096; i += 256) {
    u16 v = x[2 * i];
    int e = (v >> 7) & 0xFF;
    if (e >= 0xC0) bad++;
  }
  atomicAdd(&cnt, bad);
  __syncthreads();
  if (threadIdx.x == 0) *flag = (cnt >= 64) ? 1 : 0;
}

// ---------------- canonicalize all inputs to bf16 (linear, C-order) ----------
struct CanonJobs {
  const void* s[13];
  u16* d[13];
  int n[13];
};

__global__ __launch_bounds__(256) void canon_kernel(CanonJobs jobs,
                                                    const int* __restrict__ flag) {
  int j = blockIdx.y;
  int n = jobs.n[j];
  const void* s = jobs.s[j];
  u16* d = jobs.d[j];
  bool isf32 = (*flag != 0);
  for (int i = blockIdx.x * 256 + threadIdx.x; i < n; i += gridDim.x * 256) {
    d[i] = isf32 ? f2b(((const float*)s)[i]) : ((const u16*)s)[i];
  }
}

// ---------------- LayerNorm (bf16 input) ----------------
__global__ __launch_bounds__(256) void ln_bf16_kernel(
    const u16* __restrict__ x, const u16* __restrict__ g,
    const u16* __restrict__ b, u16* __restrict__ out) {
  int row = blockIdx.x;
  int tid = threadIdx.x;
  const u16* xr = x + (size_t)row * DMODEL;
  float v0 = b2f(xr[tid]), v1 = b2f(xr[tid + 256]), v2 = b2f(xr[tid + 512]);
  float s = v0 + v1 + v2;
  float q = v0 * v0 + v1 * v1 + v2 * v2;
#pragma unroll
  for (int off = 32; off; off >>= 1) {
    s += __shfl_xor(s, off, 64);
    q += __shfl_xor(q, off, 64);
  }
  __shared__ float rs[4], rq[4];
  int wv = tid >> 6;
  if ((tid & 63) == 0) { rs[wv] = s; rq[wv] = q; }
  __syncthreads();
  s = rs[0] + rs[1] + rs[2] + rs[3];
  q = rq[0] + rq[1] + rq[2] + rq[3];
  float mean = s * (1.0f / 768.0f);
  float var = q * (1.0f / 768.0f) - mean * mean;
  float inv = rsqrtf(var + 1e-5f);
  u16* outr = out + (size_t)row * DMODEL;
  outr[tid]       = f2b((v0 - mean) * inv * b2f(g[tid])       + b2f(b[tid]));
  outr[tid + 256] = f2b((v1 - mean) * inv * b2f(g[tid + 256]) + b2f(b[tid + 256]));
  outr[tid + 512] = f2b((v2 - mean) * inv * b2f(g[tid + 512]) + b2f(b[tid + 512]));
}

// ---------------- LayerNorm (f32 input) ----------------
__global__ __launch_bounds__(256) void ln_f32_kernel(
    const float* __restrict__ x, const u16* __restrict__ g,
    const u16* __restrict__ b, u16* __restrict__ out) {
  int row = blockIdx.x;
  int tid = threadIdx.x;
  const float* xr = x + (size_t)row * DMODEL;
  float v0 = xr[tid], v1 = xr[tid + 256], v2 = xr[tid + 512];
  float s = v0 + v1 + v2;
  float q = v0 * v0 + v1 * v1 + v2 * v2;
#pragma unroll
  for (int off = 32; off; off >>= 1) {
    s += __shfl_xor(s, off, 64);
    q += __shfl_xor(q, off, 64);
  }
  __shared__ float rs[4], rq[4];
  int wv = tid >> 6;
  if ((tid & 63) == 0) { rs[wv] = s; rq[wv] = q; }
  __syncthreads();
  s = rs[0] + rs[1] + rs[2] + rs[3];
  q = rq[0] + rq[1] + rq[2] + rq[3];
  float mean = s * (1.0f / 768.0f);
  float var = q * (1.0f / 768.0f) - mean * mean;
  float inv = rsqrtf(var + 1e-5f);
  u16* outr = out + (size_t)row * DMODEL;
  outr[tid]       = f2b((v0 - mean) * inv * b2f(g[tid])       + b2f(b[tid]));
  outr[tid + 256] = f2b((v1 - mean) * inv * b2f(g[tid + 256]) + b2f(b[tid + 256]));
  outr[tid + 512] = f2b((v2 - mean) * inv * b2f(g[tid + 512]) + b2f(b[tid + 512]));
}

// ====== shared LDS-staged 128x128 mainloop (m97 structure) ======
__device__ __forceinline__ void gemm128_mainloop(
    const u16* __restrict__ A, const u16* __restrict__ W, int K,
    int mB0, int nB0, u16* Al, u16* Bl, f32x4 (&acc)[4][4]) {
  int lane = threadIdx.x & 63;
  int wv = threadIdx.x >> 6;
  int q16 = lane & 15, quad = lane >> 4;
  int mW = (wv >> 1) * 64, nW = (wv & 1) * 64;
  int srow = lane >> 2, scol = (lane & 3) * 8;
  for (int k0 = 0; k0 < K; k0 += 32) {
#pragma unroll
    for (int c = 0; c < 2; ++c) {
      int ch = wv * 2 + c;
      int r = ch * 16 + srow;
      gl_lds16(A + (size_t)(mB0 + r) * K + k0 + scol, Al + ch * 512);
      gl_lds16(W + (size_t)(nB0 + r) * K + k0 + scol, Bl + ch * 512);
    }
    __syncthreads();
    bf16x8 af[4], bfr[4];
#pragma unroll
    for (int si = 0; si < 4; ++si)
      af[si] = *(const bf16x8*)((const __bf16*)Al + (mW + si * 16 + q16) * 32 + quad * 8);
#pragma unroll
    for (int sj = 0; sj < 4; ++sj)
      bfr[sj] = *(const bf16x8*)((const __bf16*)Bl + (nW + sj * 16 + q16) * 32 + quad * 8);
#pragma unroll
    for (int si = 0; si < 4; ++si)
#pragma unroll
      for (int sj = 0; sj < 4; ++sj)
        acc[si][sj] = __builtin_amdgcn_mfma_f32_16x16x32_bf16(af[si], bfr[sj], acc[si][sj], 0, 0, 0);
    __syncthreads();
  }
}

// ---------------- MFMA GEMM: C = A[M,K] * W[N,K]^T + bias, bf16 out ----------
__global__ __launch_bounds__(256) void gemm_bt(
    const u16* __restrict__ Ap, const u16* __restrict__ Wp,
    const u16* __restrict__ bias, u16* __restrict__ Cp, int Nn, int K) {
  __shared__ __align__(16) u16 Al[128 * 32], Bl[128 * 32];
  int lane = threadIdx.x & 63;
  int wv = threadIdx.x >> 6;
  int q16 = lane & 15, quad = lane >> 4;
  int mBase = blockIdx.y * 128 + (wv >> 1) * 64;
  int nBase = blockIdx.x * 128 + (wv & 1) * 64;
  f32x4 acc[4][4] = {};
  gemm128_mainloop(Ap, Wp, K, blockIdx.y * 128, blockIdx.x * 128, Al, Bl, acc);
#pragma unroll
  for (int si = 0; si < 4; ++si)
#pragma unroll
    for (int sj = 0; sj < 4; ++sj) {
      int col = nBase + sj * 16 + q16;
      float bcol = b2f(bias[col]);
#pragma unroll
      for (int r = 0; r < 4; ++r) {
        int rowi = mBase + si * 16 + quad * 4 + r;
        Cp[(size_t)rowi * Nn + col] = f2b(acc[si][sj][r] + bcol);
      }
    }
}

// ---------------- final MFMA GEMM: out(f32) = x1 + act @ wout^T + bias -------
__global__ __launch_bounds__(256) void gemm_out_f32(
    const u16* __restrict__ Ap, const u16* __restrict__ Wp,
    const u16* __restrict__ bias, const float* __restrict__ res,
    float* __restrict__ Cp, int Nn, int K) {
  __shared__ __align__(16) u16 Al[128 * 32], Bl[128 * 32];
  int lane = threadIdx.x & 63;
  int wv = threadIdx.x >> 6;
  int q16 = lane & 15, quad = lane >> 4;
  int mBase = blockIdx.y * 128 + (wv >> 1) * 64;
  int nBase = blockIdx.x * 128 + (wv & 1) * 64;
  f32x4 acc[4][4] = {};
  gemm128_mainloop(Ap, Wp, K, blockIdx.y * 128, blockIdx.x * 128, Al, Bl, acc);
#pragma unroll
  for (int si = 0; si < 4; ++si)
#pragma unroll
    for (int sj = 0; sj < 4; ++sj) {
      int col = nBase + sj * 16 + q16;
      float bcol = b2f(bias[col]);
#pragma unroll
      for (int r = 0; r < 4; ++r) {
        int rowi = mBase + si * 16 + quad * 4 + r;
        Cp[(size_t)rowi * Nn + col] = acc[si][sj][r] + bcol + res[(size_t)rowi * Nn + col];
      }
    }
}

// ---------------- fused FFN-in: act = silu(h2 @ Wu^T + bu) * (h2 @ Wg^T + bg)
__global__ __launch_bounds__(256) void ffn_in_kernel(
    const u16* __restrict__ hp, const u16* __restrict__ Wp,
    const u16* __restrict__ bias, u16* __restrict__ actp) {
  __shared__ __align__(16) u16 Al[128 * 32], Bl[128 * 32];
  int lane = threadIdx.x & 63;
  int wv = threadIdx.x >> 6;
  int q16 = lane & 15, quad = lane >> 4;
  int mB0 = blockIdx.y * 128;
  int cB0 = blockIdx.x * 64;
  int mW = (wv >> 1) * 64;
  int cW = (wv & 1) * 32;
  int srow = lane >> 2, scol = (lane & 3) * 8;
  f32x4 au[4][2] = {}, ag[4][2] = {};
  for (int k0 = 0; k0 < DMODEL; k0 += 32) {
#pragma unroll
    for (int c = 0; c < 2; ++c) {
      int ch = wv * 2 + c;
      int r = ch * 16 + srow;
      gl_lds16(hp + (size_t)(mB0 + r) * DMODEL + k0 + scol, Al + ch * 512);
      int grow = (r < 64) ? (cB0 + r) : (HIDDIM + cB0 + r - 64);
      gl_lds16(Wp + (size_t)grow * DMODEL + k0 + scol, Bl + ch * 512);
    }
    __syncthreads();
    bf16x8 af[4], wu[2], wg[2];
#pragma unroll
    for (int si = 0; si < 4; ++si)
      af[si] = *(const bf16x8*)((const __bf16*)Al + (mW + si * 16 + q16) * 32 + quad * 8);
#pragma unroll
    for (int sj = 0; sj < 2; ++sj) {
      wu[sj] = *(const bf16x8*)((const __bf16*)Bl + (cW + sj * 16 + q16) * 32 + quad * 8);
      wg[sj] = *(const bf16x8*)((const __bf16*)Bl + (64 + cW + sj * 16 + q16) * 32 + quad * 8);
    }
#pragma unroll
    for (int si = 0; si < 4; ++si)
#pragma unroll
      for (int sj = 0; sj < 2; ++sj) {
        au[si][sj] = __builtin_amdgcn_mfma_f32_16x16x32_bf16(af[si], wu[sj], au[si][sj], 0, 0, 0);
        ag[si][sj] = __builtin_amdgcn_mfma_f32_16x16x32_bf16(af[si], wg[sj], ag[si][sj], 0, 0, 0);
      }
    __syncthreads();
  }
#pragma unroll
  for (int si = 0; si < 4; ++si)
#pragma unroll
    for (int sj = 0; sj < 2; ++sj) {
      int col = cB0 + cW + sj * 16 + q16;
      float bu = b2f(bias[col]);
      float bg = b2f(bias[HIDDIM + col]);
#pragma unroll
      for (int r = 0; r < 4; ++r) {
        int rowi = mB0 + mW + si * 16 + quad * 4 + r;
        float u = au[si][sj][r] + bu;
        float g = ag[si][sj][r] + bg;
        float s = u / (1.0f + __expf(-u));
        actp[(size_t)rowi * HIDDIM + col] = f2b(s * g);
      }
    }
}

// ---------------- coord bias p2[b,h,n] = (coords.relw) * LOG2E ---------------
__global__ __launch_bounds__(256) void p_kernel(
    const u16* __restrict__ coords, const u16* __restrict__ relw,
    float* __restrict__ p) {
  const float LOG2E = 1.4426950408889634f;
  int idx = blockIdx.x * 256 + threadIdx.x;  // B*N = 4096
  float c0 = b2f(coords[idx * 3 + 0]);
  float c1 = b2f(coords[idx * 3 + 1]);
  float c2 = b2f(coords[idx * 3 + 2]);
  int b = idx >> 10, n = idx & 1023;
#pragma unroll
  for (int h = 0; h < NHEAD; ++h) {
    float w0 = b2f(relw[h * 3 + 0]), w1 = b2f(relw[h * 3 + 1]), w2 = b2f(relw[h * 3 + 2]);
    p[(size_t)(b * NHEAD + h) * NTOK + n] = (c0 * w0 + c1 * w1 + c2 * w2) * LOG2E;
  }
}

// ---------------- V transpose: Vt[b][h][d][n] = V[b][n][h][d] ----------------
__global__ __launch_bounds__(256) void vt_kernel(const u16* __restrict__ qkvp,
                                                 u16* __restrict__ vtp) {
  int blk = blockIdx.x;            // b*192 + h*16 + nt
  int b = blk / 192;
  int rem = blk % 192;
  int h = rem >> 4;
  int nt = rem & 15;
  int wv = threadIdx.x >> 6;
  int d = threadIdx.x & 63;
  int n0 = nt * 64 + wv * 16;
  const u16* src = qkvp + ((size_t)(b * NTOK) + n0) * LD3 + 2 * DMODEL + h * 64 + d;
  u16* dst = vtp + ((size_t)((b * NHEAD + h) * 64 + d)) * NTOK + n0;
#pragma unroll
  for (int c = 0; c < 2; ++c) {
    u16 buf[8] __attribute__((aligned(16)));
#pragma unroll
    for (int i = 0; i < 8; ++i) buf[i] = src[(size_t)(c * 8 + i) * LD3];
    *(uint4*)(dst + c * 8) = *(const uint4*)buf;
  }
}

// ---------------- flash attention: block-cooperative LDS-staged K/V ----------
// Block = 4 waves, all sharing one (b,h); each wave owns a 16-row query tile.
// Per 32-token KV step: stage K[32][64] + Vt[64][32] into LDS (gl_lds16,
// 1KB coalesced per wave per matrix), double-buffered, stage issued before
// compute so HBM latency hides under MFMA/softmax. LDS slot-XOR swizzle with
// inverse applied to the per-lane GLOBAL address (dest stays linear).
__global__ __launch_bounds__(256) void attn_kernel(
    const u16* __restrict__ qkvp, const u16* __restrict__ vtp,
    const float* __restrict__ p2, const u16* __restrict__ xp,
    float* __restrict__ x1) {
  const __bf16* qb = (const __bf16*)qkvp;
  __shared__ __align__(16) u16 Kl[2][32 * 64];   // [j][d], 16B-slot swizzled by j&7
  __shared__ __align__(16) u16 Vl[2][64 * 32];   // [d][j], 16B-slot swizzled by d&3
  __shared__ __align__(16) u16 Pl[4][16][40];    // 80B row stride
  int lane = threadIdx.x & 63;
  int wv = threadIdx.x >> 6;
  int blk = blockIdx.x;                    // 0..767, 16 blocks per (b,h)
  int b = blk / 192;
  int rem = blk % 192;
  int h = rem >> 4;
  int i0 = ((rem & 15) * 4 + wv) * 16;     // wave's query tile
  int q16 = lane & 15, quad = lane >> 4;

  const float scl2 = 0.125f * 1.4426950408889634f;

  // Q = B-operand (rows at q16)
  const __bf16* qrow = qb + ((size_t)(b * NTOK) + i0 + q16) * LD3 + h * 64;
  bf16x8 bq0 = *(const bf16x8*)(qrow + quad * 8);
  bf16x8 bq1 = *(const bf16x8*)(qrow + 32 + quad * 8);

  const float* prow = p2 + (size_t)(b * NHEAD + h) * NTOK;

  // ---- staging addresses (per-lane global src carries the inverse swizzle) --
  int krw = wv * 8 + (lane >> 3);          // K row 0..31 (this lane stages)
  int ks  = (lane & 7) ^ (krw & 7);        // swizzled 16B slot (8 per 128B row)
  const u16* kg0 = qkvp + (size_t)(b * NTOK) * LD3 + DMODEL + h * 64 + ks * 8;
  int vrw = wv * 16 + (lane >> 2);         // Vt row (d) 0..63
  int vs  = (lane & 3) ^ (vrw & 3);        // swizzled 16B slot (4 per 64B row)
  const u16* vg0 = vtp + ((size_t)((b * NHEAD + h) * 64 + vrw)) * NTOK + vs * 8;

  float mrun = -1e30f, lsum = 0.f;
  f32x4 accO[4] = {};

  // prologue: stage tile 0
  gl_lds16(kg0 + (size_t)krw * LD3, &Kl[0][wv * 512]);
  gl_lds16(vg0, &Vl[0][wv * 512]);
  __syncthreads();

  int buf = 0;
  for (int t = 0; t < 32; ++t) {
    int j0 = t * 32;
    if (t < 31) {  // stage next tile into the other buffer (async)
      gl_lds16(kg0 + (size_t)(j0 + 32 + krw) * LD3, &Kl[buf ^ 1][wv * 512]);
      gl_lds16(vg0 + j0 + 32, &Vl[buf ^ 1][wv * 512]);
    }

    const __bf16* Kb = (const __bf16*)Kl[buf];
    int kx0 = (quad ^ (q16 & 7)) << 3;       // slot for d 0..31
    int kx1 = ((4 | quad) ^ (q16 & 7)) << 3; // slot for d 32..63
    bf16x8 ka00 = *(const bf16x8*)(Kb + q16 * 64 + kx0);
    bf16x8 ka01 = *(const bf16x8*)(Kb + q16 * 64 + kx1);
    bf16x8 ka10 = *(const bf16x8*)(Kb + (16 + q16) * 64 + kx0);
    bf16x8 ka11 = *(const bf16x8*)(Kb + (16 + q16) * 64 + kx1);
    f32x4 st0 = {}, st1 = {};
    st0 = __builtin_amdgcn_mfma_f32_16x16x32_bf16(ka00, bq0, st0, 0, 0, 0);
    st0 = __builtin_amdgcn_mfma_f32_16x16x32_bf16(ka01, bq1, st0, 0, 0, 0);
    st1 = __builtin_amdgcn_mfma_f32_16x16x32_bf16(ka10, bq0, st1, 0, 0, 0);
    st1 = __builtin_amdgcn_mfma_f32_16x16x32_bf16(ka11, bq1, st1, 0, 0, 0);

    f32x4 pjl = *(const f32x4*)(prow + j0 + 4 * quad);
    f32x4 pjh = *(const f32x4*)(prow + j0 + 16 + 4 * quad);
    float sl[4], sh[4];
#pragma unroll
    for (int r = 0; r < 4; ++r) {
      sl[r] = st0[r] * scl2 - pjl[r];
      sh[r] = st1[r] * scl2 - pjh[r];
    }
    float lm = fmaxf(fmaxf(fmaxf(sl[0], sl[1]), fmaxf(sl[2], sl[3])),
                     fmaxf(fmaxf(sh[0], sh[1]), fmaxf(sh[2], sh[3])));
    lm = fmaxf(lm, __shfl_xor(lm, 16, 64));
    lm = fmaxf(lm, __shfl_xor(lm, 32, 64));
    float mn = fmaxf(mrun, lm);
    float alpha = exp2f(mrun - mn);
    mrun = mn;
    float pl[4], ph[4];
#pragma unroll
    for (int r = 0; r < 4; ++r) {
      pl[r] = exp2f(sl[r] - mn);
      ph[r] = exp2f(sh[r] - mn);
    }
    float ts = (pl[0] + pl[1]) + (pl[2] + pl[3]) +
               (ph[0] + ph[1]) + (ph[2] + ph[3]);
    ts += __shfl_xor(ts, 16, 64);
    ts += __shfl_xor(ts, 32, 64);
    lsum = lsum * alpha + ts;

    bf16x4 w0 = {(__bf16)pl[0], (__bf16)pl[1], (__bf16)pl[2], (__bf16)pl[3]};
    bf16x4 w1 = {(__bf16)ph[0], (__bf16)ph[1], (__bf16)ph[2], (__bf16)ph[3]};
    *(bf16x4*)(&Pl[wv][q16][4 * quad]) = w0;
    *(bf16x4*)(&Pl[wv][q16][16 + 4 * quad]) = w1;
    bf16x8 ap = *(const bf16x8*)(&Pl[wv][q16][quad * 8]);

    const __bf16* Vb = (const __bf16*)Vl[buf];
    int vx = (quad ^ (q16 & 3)) << 3;        // swizzled j-slot
#pragma unroll
    for (int ds = 0; ds < 4; ++ds) {
      bf16x8 av = *(const bf16x8*)(Vb + (ds * 16 + q16) * 32 + vx);
      f32x4 c = accO[ds];
#pragma unroll
      for (int r = 0; r < 4; ++r) c[r] *= alpha;
      accO[ds] = __builtin_amdgcn_mfma_f32_16x16x32_bf16(av, ap, c, 0, 0, 0);
    }

    __syncthreads();   // next-tile loads landed (hidden under compute);
    buf ^= 1;          // all waves done reading buf -> safe to overwrite
  }

  float rl = 1.0f / lsum;
  size_t rowbase = ((size_t)(b * NTOK) + i0 + q16) * DMODEL + h * 64;
#pragma unroll
  for (int ds = 0; ds < 4; ++ds) {
    int d0 = ds * 16 + quad * 4;
    u16x4 xv = *(const u16x4*)(xp + rowbase + d0);
    f32x4 ov;
#pragma unroll
    for (int r = 0; r < 4; ++r) ov[r] = b2f(xv[r]) + accO[ds][r] * rl;
    *(f32x4*)(x1 + rowbase + d0) = ov;
  }
}

extern "C" void kernel_launch(void* const* d_in, const int* in_sizes, int n_in,
                              void* d_out, int out_size, void* d_ws, size_t ws_size,
                              hipStream_t stream) {
  // ---- host-side boundary tripwires (verified passing in R6) ----
  static const int esz[13] = {3145728, 12288, 768, 768, 1769472, 2304, 36,
                              768, 768, 3145728, 4096, 1572864, 768};
  float sig = -1.f;
  if (n_in != 13) {
    sig = 6000.f + 100.f * (float)n_in;
  } else {
    for (int i = 0; i < 13; ++i)
      if (in_sizes[i] != esz[i]) { sig = 1000.f + 100.f * (float)i; break; }
  }
  if (sig < 0.f && ws_size < 57258496ULL) sig = 3000.f;
  if (sig < 0.f && out_size != 3145728) sig = 3100.f;
  if (sig >= 0.f) {
    signal_kernel<<<(out_size + 255) / 256, 256, 0, stream>>>((float*)d_out, out_size, sig);
    return;
  }

  char* ws = (char*)d_ws;
  int*  flag    = (int*)ws;                       // 256 B
  u16*  cx      = (u16*)(ws + 256);               // 6291456
  u16*  cqkvw   = (u16*)(ws + 6291712);           // 3538944
  u16*  cwinw   = (u16*)(ws + 9830656);           // 6291456
  u16*  cwoutw  = (u16*)(ws + 16122112);          // 3145728
  u16*  ccoords = (u16*)(ws + 19267840);          // 24576
  u16*  cln1g   = (u16*)(ws + 19292416);          // 1536
  u16*  cln1b   = (u16*)(ws + 19293952);          // 1536
  u16*  cqkvb   = (u16*)(ws + 19295488);          // 4608
  u16*  crelw   = (u16*)(ws + 19300096);          // 72 (padded)
  u16*  cln2g   = (u16*)(ws + 19300352);          // 1536
  u16*  cln2b   = (u16*)(ws + 19301888);          // 1536
  u16*  cwinb   = (u16*)(ws + 19303424);          // 8192
  u16*  cwoutb  = (u16*)(ws + 19311616);          // 1536
  u16*  h       = (u16*)(ws + 19313152);          // 6291456 (LN out; dead between
                                                  //  gemm_bt and ln2 -> reused as Vt)
  u16*  qkv     = (u16*)(ws + 25604608);          // 18874368 (reused as act)
  float* pbuf   = (float*)(ws + 44478976);        // 196608
  float* x1     = (float*)(ws + 44675584);        // 12582912 -> end 57258496
  u16*  act     = qkv;
  u16*  vt      = h;   // Vt needs 4*12*64*1024*2 = 6291456 B == sizeof(h)

  // 0a. dtype flag (f32 confirmed; adaptive kept as insurance)
  detect_kernel<<<1, 256, 0, stream>>>((const u16*)d_in[0], flag);

  // 0b. canonicalize all 13 inputs to bf16 (linear C-order)
  CanonJobs jobs;
  u16* dsts[13] = {cx, ccoords, cln1g, cln1b, cqkvw, cqkvb, crelw,
                   cln2g, cln2b, cwinw, cwinb, cwoutw, cwoutb};
  for (int i = 0; i < 13; ++i) {
    jobs.s[i] = d_in[i];
    jobs.d[i] = dsts[i];
    jobs.n[i] = in_sizes[i];
  }
  canon_kernel<<<dim3(3072, 13), 256, 0, stream>>>(jobs, flag);

  // 1. h = LN1(x)
  ln_bf16_kernel<<<4096, 256, 0, stream>>>(cx, cln1g, cln1b, h);
  // 2. qkv = h @ qkv_w^T + qkv_b   (M=4096, N=2304, K=768)
  gemm_bt<<<dim3(18, 32), 256, 0, stream>>>(h, cqkvw, cqkvb, qkv, 2304, 768);
  // 3. p2[b,h,n] (pre-scaled by LOG2E)
  p_kernel<<<16, 256, 0, stream>>>(ccoords, crelw, pbuf);
  // 3b. Vt[b][h][d][n] = V  (h buffer is dead here; gemm_bt already consumed it)
  vt_kernel<<<768, 256, 0, stream>>>(qkv, vt);
  // 4. x1 = x + attention(qkv, Vt, p2)   (768 blocks; block-cooperative staging)
  attn_kernel<<<768, 256, 0, stream>>>(qkv, vt, pbuf, cx, x1);
  // 5. h2 = LN2(x1)  (reuse h)
  ln_f32_kernel<<<4096, 256, 0, stream>>>(x1, cln2g, cln2b, h);
  // 6+7. act = silu(h2 @ Wu^T + bu) * (h2 @ Wg^T + bg)   (fused, LDS-staged)
  ffn_in_kernel<<<dim3(32, 32), 256, 0, stream>>>(h, cwinw, cwinb, act);
  // 8. out(F32) = x1 + act @ wout_w^T + wout_b   (M=4096, N=768, K=2048)
  gemm_out_f32<<<dim3(6, 32), 256, 0, stream>>>(act, cwoutw, cwoutb, x1, (float*)d_out, 768, 2048);
}

// Round 6
// 293.282 us; speedup vs baseline: 1.5471x; 1.0336x over previous
//
#include <hip/hip_runtime.h>
#include <math.h>

typedef unsigned short u16;
typedef __bf16 bf16x8 __attribute__((ext_vector_type(8)));
typedef __bf16 bf16x4 __attribute__((ext_vector_type(4)));
typedef u16 u16x4 __attribute__((ext_vector_type(4)));
typedef float f32x4 __attribute__((ext_vector_type(4)));

// ---- constants ----
// B=4, N=1024, D=768, H=12, Dh=64, HID=2048, 3D=2304
#define NTOK 1024
#define DMODEL 768
#define NHEAD 12
#define LD3 2304
#define HIDDIM 2048

__device__ __forceinline__ float b2f(u16 u) {
  unsigned int t = ((unsigned int)u) << 16;
  float f;
  __builtin_memcpy(&f, &t, 4);
  return f;
}
__device__ __forceinline__ u16 f2b(float f) {
  unsigned int t;
  __builtin_memcpy(&t, &f, 4);
  t += 0x7fffu + ((t >> 16) & 1u);
  return (u16)(t >> 16);
}

// async global->LDS, 16B per lane; LDS dest is wave-uniform base + lane*16
__device__ __forceinline__ void gl_lds16(const u16* g, u16* l) {
  __builtin_amdgcn_global_load_lds(
      (__attribute__((address_space(1))) const unsigned int*)g,
      (__attribute__((address_space(3))) unsigned int*)l, 16, 0, 0);
}

// ---------------- host-assert signal (f32 output now) ------------------------
__global__ __launch_bounds__(256) void signal_kernel(float* __restrict__ out,
                                                     int n, float c) {
  int i = blockIdx.x * 256 + threadIdx.x;
  if (i < n) out[i] = c;
}

// ---------------- input dtype detection (verified f32: flag=1, R6) -----------
__global__ __launch_bounds__(256) void detect_kernel(const u16* __restrict__ x,
                                                     int* __restrict__ flag) {
  __shared__ int cnt;
  if (threadIdx.x == 0) cnt = 0;
  __syncthreads();
  int bad = 0;
  for (int i = threadIdx.x; i < 4096; i += 256) {
    u16 v = x[2 * i];
    int e = (v >> 7) & 0xFF;
    if (e >= 0xC0) bad++;
  }
  atomicAdd(&cnt, bad);
  __syncthreads();
  if (threadIdx.x == 0) *flag = (cnt >= 64) ? 1 : 0;
}

// ---------------- canonicalize all inputs to bf16 (linear, C-order) ----------
struct CanonJobs {
  const void* s[13];
  u16* d[13];
  int n[13];
};

__global__ __launch_bounds__(256) void canon_kernel(CanonJobs jobs,
                                                    const int* __restrict__ flag) {
  int j = blockIdx.y;
  int n = jobs.n[j];
  const void* s = jobs.s[j];
  u16* d = jobs.d[j];
  bool isf32 = (*flag != 0);
  for (int i = blockIdx.x * 256 + threadIdx.x; i < n; i += gridDim.x * 256) {
    d[i] = isf32 ? f2b(((const float*)s)[i]) : ((const u16*)s)[i];
  }
}

// ---------------- LayerNorm (bf16 input) ----------------
__global__ __launch_bounds__(256) void ln_bf16_kernel(
    const u16* __restrict__ x, const u16* __restrict__ g,
    const u16* __restrict__ b, u16* __restrict__ out) {
  int row = blockIdx.x;
  int tid = threadIdx.x;
  const u16* xr = x + (size_t)row * DMODEL;
  float v0 = b2f(xr[tid]), v1 = b2f(xr[tid + 256]), v2 = b2f(xr[tid + 512]);
  float s = v0 + v1 + v2;
  float q = v0 * v0 + v1 * v1 + v2 * v2;
#pragma unroll
  for (int off = 32; off; off >>= 1) {
    s += __shfl_xor(s, off, 64);
    q += __shfl_xor(q, off, 64);
  }
  __shared__ float rs[4], rq[4];
  int wv = tid >> 6;
  if ((tid & 63) == 0) { rs[wv] = s; rq[wv] = q; }
  __syncthreads();
  s = rs[0] + rs[1] + rs[2] + rs[3];
  q = rq[0] + rq[1] + rq[2] + rq[3];
  float mean = s * (1.0f / 768.0f);
  float var = q * (1.0f / 768.0f) - mean * mean;
  float inv = rsqrtf(var + 1e-5f);
  u16* outr = out + (size_t)row * DMODEL;
  outr[tid]       = f2b((v0 - mean) * inv * b2f(g[tid])       + b2f(b[tid]));
  outr[tid + 256] = f2b((v1 - mean) * inv * b2f(g[tid + 256]) + b2f(b[tid + 256]));
  outr[tid + 512] = f2b((v2 - mean) * inv * b2f(g[tid + 512]) + b2f(b[tid + 512]));
}

// ---------------- LayerNorm (f32 input) ----------------
__global__ __launch_bounds__(256) void ln_f32_kernel(
    const float* __restrict__ x, const u16* __restrict__ g,
    const u16* __restrict__ b, u16* __restrict__ out) {
  int row = blockIdx.x;
  int tid = threadIdx.x;
  const float* xr = x + (size_t)row * DMODEL;
  float v0 = xr[tid], v1 = xr[tid + 256], v2 = xr[tid + 512];
  float s = v0 + v1 + v2;
  float q = v0 * v0 + v1 * v1 + v2 * v2;
#pragma unroll
  for (int off = 32; off; off >>= 1) {
    s += __shfl_xor(s, off, 64);
    q += __shfl_xor(q, off, 64);
  }
  __shared__ float rs[4], rq[4];
  int wv = tid >> 6;
  if ((tid & 63) == 0) { rs[wv] = s; rq[wv] = q; }
  __syncthreads();
  s = rs[0] + rs[1] + rs[2] + rs[3];
  q = rq[0] + rq[1] + rq[2] + rq[3];
  float mean = s * (1.0f / 768.0f);
  float var = q * (1.0f / 768.0f) - mean * mean;
  float inv = rsqrtf(var + 1e-5f);
  u16* outr = out + (size_t)row * DMODEL;
  outr[tid]       = f2b((v0 - mean) * inv * b2f(g[tid])       + b2f(b[tid]));
  outr[tid + 256] = f2b((v1 - mean) * inv * b2f(g[tid + 256]) + b2f(b[tid + 256]));
  outr[tid + 512] = f2b((v2 - mean) * inv * b2f(g[tid + 512]) + b2f(b[tid + 512]));
}

// ====== shared LDS-staged 128x128 mainloop (m97 structure) ======
__device__ __forceinline__ void gemm128_mainloop(
    const u16* __restrict__ A, const u16* __restrict__ W, int K,
    int mB0, int nB0, u16* Al, u16* Bl, f32x4 (&acc)[4][4]) {
  int lane = threadIdx.x & 63;
  int wv = threadIdx.x >> 6;
  int q16 = lane & 15, quad = lane >> 4;
  int mW = (wv >> 1) * 64, nW = (wv & 1) * 64;
  int srow = lane >> 2, scol = (lane & 3) * 8;
  for (int k0 = 0; k0 < K; k0 += 32) {
#pragma unroll
    for (int c = 0; c < 2; ++c) {
      int ch = wv * 2 + c;
      int r = ch * 16 + srow;
      gl_lds16(A + (size_t)(mB0 + r) * K + k0 + scol, Al + ch * 512);
      gl_lds16(W + (size_t)(nB0 + r) * K + k0 + scol, Bl + ch * 512);
    }
    __syncthreads();
    bf16x8 af[4], bfr[4];
#pragma unroll
    for (int si = 0; si < 4; ++si)
      af[si] = *(const bf16x8*)((const __bf16*)Al + (mW + si * 16 + q16) * 32 + quad * 8);
#pragma unroll
    for (int sj = 0; sj < 4; ++sj)
      bfr[sj] = *(const bf16x8*)((const __bf16*)Bl + (nW + sj * 16 + q16) * 32 + quad * 8);
#pragma unroll
    for (int si = 0; si < 4; ++si)
#pragma unroll
      for (int sj = 0; sj < 4; ++sj)
        acc[si][sj] = __builtin_amdgcn_mfma_f32_16x16x32_bf16(af[si], bfr[sj], acc[si][sj], 0, 0, 0);
    __syncthreads();
  }
}

// ---------------- MFMA GEMM: C = A[M,K] * W[N,K]^T + bias, bf16 out ----------
__global__ __launch_bounds__(256) void gemm_bt(
    const u16* __restrict__ Ap, const u16* __restrict__ Wp,
    const u16* __restrict__ bias, u16* __restrict__ Cp, int Nn, int K) {
  __shared__ __align__(16) u16 Al[128 * 32], Bl[128 * 32];
  int lane = threadIdx.x & 63;
  int wv = threadIdx.x >> 6;
  int q16 = lane & 15, quad = lane >> 4;
  int mBase = blockIdx.y * 128 + (wv >> 1) * 64;
  int nBase = blockIdx.x * 128 + (wv & 1) * 64;
  f32x4 acc[4][4] = {};
  gemm128_mainloop(Ap, Wp, K, blockIdx.y * 128, blockIdx.x * 128, Al, Bl, acc);
#pragma unroll
  for (int si = 0; si < 4; ++si)
#pragma unroll
    for (int sj = 0; sj < 4; ++sj) {
      int col = nBase + sj * 16 + q16;
      float bcol = b2f(bias[col]);
#pragma unroll
      for (int r = 0; r < 4; ++r) {
        int rowi = mBase + si * 16 + quad * 4 + r;
        Cp[(size_t)rowi * Nn + col] = f2b(acc[si][sj][r] + bcol);
      }
    }
}

// ---------------- final GEMM, split-K x 2, N-tile 64: 768 blocks -------------
// grid (12, 32, 2). Block = 128M x 64N, K-half = 1024 (32 K-steps).
// kz=0 -> raw partial to part[]; kz=1 -> acc + bias + res to out[].
// add_kernel then does out += part.
__global__ __launch_bounds__(256) void gemm_out_split(
    const u16* __restrict__ Ap, const u16* __restrict__ Wp,
    const u16* __restrict__ bias, const float* __restrict__ res,
    float* __restrict__ part, float* __restrict__ out) {
  __shared__ __align__(16) u16 Al[128 * 32], Bl[64 * 32];
  int lane = threadIdx.x & 63;
  int wv = threadIdx.x >> 6;
  int q16 = lane & 15, quad = lane >> 4;
  int mB0 = blockIdx.y * 128;
  int nB0 = blockIdx.x * 64;
  int kz = blockIdx.z;
  int kbase = kz * 1024;
  int mW = (wv >> 1) * 64, nW = (wv & 1) * 32;
  int srow = lane >> 2, scol = (lane & 3) * 8;
  f32x4 acc[4][2] = {};
  for (int k0 = 0; k0 < 1024; k0 += 32) {
#pragma unroll
    for (int c = 0; c < 2; ++c) {
      int ch = wv * 2 + c;
      int r = ch * 16 + srow;
      gl_lds16(Ap + (size_t)(mB0 + r) * 2048 + kbase + k0 + scol, Al + ch * 512);
    }
    {
      int r = wv * 16 + srow;
      gl_lds16(Wp + (size_t)(nB0 + r) * 2048 + kbase + k0 + scol, Bl + wv * 512);
    }
    __syncthreads();
    bf16x8 af[4], bfr[2];
#pragma unroll
    for (int si = 0; si < 4; ++si)
      af[si] = *(const bf16x8*)((const __bf16*)Al + (mW + si * 16 + q16) * 32 + quad * 8);
#pragma unroll
    for (int sj = 0; sj < 2; ++sj)
      bfr[sj] = *(const bf16x8*)((const __bf16*)Bl + (nW + sj * 16 + q16) * 32 + quad * 8);
#pragma unroll
    for (int si = 0; si < 4; ++si)
#pragma unroll
      for (int sj = 0; sj < 2; ++sj)
        acc[si][sj] = __builtin_amdgcn_mfma_f32_16x16x32_bf16(af[si], bfr[sj], acc[si][sj], 0, 0, 0);
    __syncthreads();
  }
#pragma unroll
  for (int si = 0; si < 4; ++si)
#pragma unroll
    for (int sj = 0; sj < 2; ++sj) {
      int col = nB0 + nW + sj * 16 + q16;
#pragma unroll
      for (int r = 0; r < 4; ++r) {
        int rowi = mB0 + mW + si * 16 + quad * 4 + r;
        size_t idx = (size_t)rowi * 768 + col;
        if (kz == 0) {
          part[idx] = acc[si][sj][r];
        } else {
          out[idx] = acc[si][sj][r] + b2f(bias[col]) + res[idx];
        }
      }
    }
}

// ---------------- out += part (vectorized, 3.1M floats) ----------------------
__global__ __launch_bounds__(256) void add_kernel(float* __restrict__ out,
                                                  const float* __restrict__ part) {
  int i = blockIdx.x * 256 + threadIdx.x;   // 786432 f32x4 elems -> 3072 blocks
  f32x4 o = ((f32x4*)out)[i];
  f32x4 p = ((const f32x4*)part)[i];
#pragma unroll
  for (int r = 0; r < 4; ++r) o[r] += p[r];
  ((f32x4*)out)[i] = o;
}

// ---------------- fused FFN-in: act = silu(h2 @ Wu^T + bu) * (h2 @ Wg^T + bg)
__global__ __launch_bounds__(256) void ffn_in_kernel(
    const u16* __restrict__ hp, const u16* __restrict__ Wp,
    const u16* __restrict__ bias, u16* __restrict__ actp) {
  __shared__ __align__(16) u16 Al[128 * 32], Bl[128 * 32];
  int lane = threadIdx.x & 63;
  int wv = threadIdx.x >> 6;
  int q16 = lane & 15, quad = lane >> 4;
  int mB0 = blockIdx.y * 128;
  int cB0 = blockIdx.x * 64;
  int mW = (wv >> 1) * 64;
  int cW = (wv & 1) * 32;
  int srow = lane >> 2, scol = (lane & 3) * 8;
  f32x4 au[4][2] = {}, ag[4][2] = {};
  for (int k0 = 0; k0 < DMODEL; k0 += 32) {
#pragma unroll
    for (int c = 0; c < 2; ++c) {
      int ch = wv * 2 + c;
      int r = ch * 16 + srow;
      gl_lds16(hp + (size_t)(mB0 + r) * DMODEL + k0 + scol, Al + ch * 512);
      int grow = (r < 64) ? (cB0 + r) : (HIDDIM + cB0 + r - 64);
      gl_lds16(Wp + (size_t)grow * DMODEL + k0 + scol, Bl + ch * 512);
    }
    __syncthreads();
    bf16x8 af[4], wu[2], wg[2];
#pragma unroll
    for (int si = 0; si < 4; ++si)
      af[si] = *(const bf16x8*)((const __bf16*)Al + (mW + si * 16 + q16) * 32 + quad * 8);
#pragma unroll
    for (int sj = 0; sj < 2; ++sj) {
      wu[sj] = *(const bf16x8*)((const __bf16*)Bl + (cW + sj * 16 + q16) * 32 + quad * 8);
      wg[sj] = *(const bf16x8*)((const __bf16*)Bl + (64 + cW + sj * 16 + q16) * 32 + quad * 8);
    }
#pragma unroll
    for (int si = 0; si < 4; ++si)
#pragma unroll
      for (int sj = 0; sj < 2; ++sj) {
        au[si][sj] = __builtin_amdgcn_mfma_f32_16x16x32_bf16(af[si], wu[sj], au[si][sj], 0, 0, 0);
        ag[si][sj] = __builtin_amdgcn_mfma_f32_16x16x32_bf16(af[si], wg[sj], ag[si][sj], 0, 0, 0);
      }
    __syncthreads();
  }
#pragma unroll
  for (int si = 0; si < 4; ++si)
#pragma unroll
    for (int sj = 0; sj < 2; ++sj) {
      int col = cB0 + cW + sj * 16 + q16;
      float bu = b2f(bias[col]);
      float bg = b2f(bias[HIDDIM + col]);
#pragma unroll
      for (int r = 0; r < 4; ++r) {
        int rowi = mB0 + mW + si * 16 + quad * 4 + r;
        float u = au[si][sj][r] + bu;
        float g = ag[si][sj][r] + bg;
        float s = u / (1.0f + __expf(-u));
        actp[(size_t)rowi * HIDDIM + col] = f2b(s * g);
      }
    }
}

// ---------------- coord bias p2[b,h,n] = (coords.relw) * LOG2E ---------------
__global__ __launch_bounds__(256) void p_kernel(
    const u16* __restrict__ coords, const u16* __restrict__ relw,
    float* __restrict__ p) {
  const float LOG2E = 1.4426950408889634f;
  int idx = blockIdx.x * 256 + threadIdx.x;  // B*N = 4096
  float c0 = b2f(coords[idx * 3 + 0]);
  float c1 = b2f(coords[idx * 3 + 1]);
  float c2 = b2f(coords[idx * 3 + 2]);
  int b = idx >> 10, n = idx & 1023;
#pragma unroll
  for (int h = 0; h < NHEAD; ++h) {
    float w0 = b2f(relw[h * 3 + 0]), w1 = b2f(relw[h * 3 + 1]), w2 = b2f(relw[h * 3 + 2]);
    p[(size_t)(b * NHEAD + h) * NTOK + n] = (c0 * w0 + c1 * w1 + c2 * w2) * LOG2E;
  }
}

// ---------------- V transpose: Vt[b][h][d][n] = V[b][n][h][d] ----------------
__global__ __launch_bounds__(256) void vt_kernel(const u16* __restrict__ qkvp,
                                                 u16* __restrict__ vtp) {
  int blk = blockIdx.x;            // b*192 + h*16 + nt
  int b = blk / 192;
  int rem = blk % 192;
  int h = rem >> 4;
  int nt = rem & 15;
  int wv = threadIdx.x >> 6;
  int d = threadIdx.x & 63;
  int n0 = nt * 64 + wv * 16;
  const u16* src = qkvp + ((size_t)(b * NTOK) + n0) * LD3 + 2 * DMODEL + h * 64 + d;
  u16* dst = vtp + ((size_t)((b * NHEAD + h) * 64 + d)) * NTOK + n0;
#pragma unroll
  for (int c = 0; c < 2; ++c) {
    u16 buf[8] __attribute__((aligned(16)));
#pragma unroll
    for (int i = 0; i < 8; ++i) buf[i] = src[(size_t)(c * 8 + i) * LD3];
    *(uint4*)(dst + c * 8) = *(const uint4*)buf;
  }
}

// ---------------- flash attention: block-cooperative LDS-staged K/V ----------
__global__ __launch_bounds__(256) void attn_kernel(
    const u16* __restrict__ qkvp, const u16* __restrict__ vtp,
    const float* __restrict__ p2, const u16* __restrict__ xp,
    float* __restrict__ x1) {
  const __bf16* qb = (const __bf16*)qkvp;
  __shared__ __align__(16) u16 Kl[2][32 * 64];   // [j][d], 16B-slot swizzled by j&7
  __shared__ __align__(16) u16 Vl[2][64 * 32];   // [d][j], 16B-slot swizzled by d&3
  __shared__ __align__(16) u16 Pl[4][16][40];    // 80B row stride
  int lane = threadIdx.x & 63;
  int wv = threadIdx.x >> 6;
  int blk = blockIdx.x;                    // 0..767, 16 blocks per (b,h)
  int b = blk / 192;
  int rem = blk % 192;
  int h = rem >> 4;
  int i0 = ((rem & 15) * 4 + wv) * 16;     // wave's query tile
  int q16 = lane & 15, quad = lane >> 4;

  const float scl2 = 0.125f * 1.4426950408889634f;

  const __bf16* qrow = qb + ((size_t)(b * NTOK) + i0 + q16) * LD3 + h * 64;
  bf16x8 bq0 = *(const bf16x8*)(qrow + quad * 8);
  bf16x8 bq1 = *(const bf16x8*)(qrow + 32 + quad * 8);

  const float* prow = p2 + (size_t)(b * NHEAD + h) * NTOK;

  int krw = wv * 8 + (lane >> 3);          // K row 0..31 (this lane stages)
  int ks  = (lane & 7) ^ (krw & 7);        // swizzled 16B slot (8 per 128B row)
  const u16* kg0 = qkvp + (size_t)(b * NTOK) * LD3 + DMODEL + h * 64 + ks * 8;
  int vrw = wv * 16 + (lane >> 2);         // Vt row (d) 0..63
  int vs  = (lane & 3) ^ (vrw & 3);        // swizzled 16B slot (4 per 64B row)
  const u16* vg0 = vtp + ((size_t)((b * NHEAD + h) * 64 + vrw)) * NTOK + vs * 8;

  float mrun = -1e30f, lsum = 0.f;
  f32x4 accO[4] = {};

  gl_lds16(kg0 + (size_t)krw * LD3, &Kl[0][wv * 512]);
  gl_lds16(vg0, &Vl[0][wv * 512]);
  __syncthreads();

  int buf = 0;
  for (int t = 0; t < 32; ++t) {
    int j0 = t * 32;
    if (t < 31) {
      gl_lds16(kg0 + (size_t)(j0 + 32 + krw) * LD3, &Kl[buf ^ 1][wv * 512]);
      gl_lds16(vg0 + j0 + 32, &Vl[buf ^ 1][wv * 512]);
    }

    const __bf16* Kb = (const __bf16*)Kl[buf];
    int kx0 = (quad ^ (q16 & 7)) << 3;
    int kx1 = ((4 | quad) ^ (q16 & 7)) << 3;
    bf16x8 ka00 = *(const bf16x8*)(Kb + q16 * 64 + kx0);
    bf16x8 ka01 = *(const bf16x8*)(Kb + q16 * 64 + kx1);
    bf16x8 ka10 = *(const bf16x8*)(Kb + (16 + q16) * 64 + kx0);
    bf16x8 ka11 = *(const bf16x8*)(Kb + (16 + q16) * 64 + kx1);
    f32x4 st0 = {}, st1 = {};
    st0 = __builtin_amdgcn_mfma_f32_16x16x32_bf16(ka00, bq0, st0, 0, 0, 0);
    st0 = __builtin_amdgcn_mfma_f32_16x16x32_bf16(ka01, bq1, st0, 0, 0, 0);
    st1 = __builtin_amdgcn_mfma_f32_16x16x32_bf16(ka10, bq0, st1, 0, 0, 0);
    st1 = __builtin_amdgcn_mfma_f32_16x16x32_bf16(ka11, bq1, st1, 0, 0, 0);

    f32x4 pjl = *(const f32x4*)(prow + j0 + 4 * quad);
    f32x4 pjh = *(const f32x4*)(prow + j0 + 16 + 4 * quad);
    float sl[4], sh[4];
#pragma unroll
    for (int r = 0; r < 4; ++r) {
      sl[r] = st0[r] * scl2 - pjl[r];
      sh[r] = st1[r] * scl2 - pjh[r];
    }
    float lm = fmaxf(fmaxf(fmaxf(sl[0], sl[1]), fmaxf(sl[2], sl[3])),
                     fmaxf(fmaxf(sh[0], sh[1]), fmaxf(sh[2], sh[3])));
    lm = fmaxf(lm, __shfl_xor(lm, 16, 64));
    lm = fmaxf(lm, __shfl_xor(lm, 32, 64));
    float mn = fmaxf(mrun, lm);
    float alpha = exp2f(mrun - mn);
    mrun = mn;
    float pl[4], ph[4];
#pragma unroll
    for (int r = 0; r < 4; ++r) {
      pl[r] = exp2f(sl[r] - mn);
      ph[r] = exp2f(sh[r] - mn);
    }
    float ts = (pl[0] + pl[1]) + (pl[2] + pl[3]) +
               (ph[0] + ph[1]) + (ph[2] + ph[3]);
    ts += __shfl_xor(ts, 16, 64);
    ts += __shfl_xor(ts, 32, 64);
    lsum = lsum * alpha + ts;

    bf16x4 w0 = {(__bf16)pl[0], (__bf16)pl[1], (__bf16)pl[2], (__bf16)pl[3]};
    bf16x4 w1 = {(__bf16)ph[0], (__bf16)ph[1], (__bf16)ph[2], (__bf16)ph[3]};
    *(bf16x4*)(&Pl[wv][q16][4 * quad]) = w0;
    *(bf16x4*)(&Pl[wv][q16][16 + 4 * quad]) = w1;
    bf16x8 ap = *(const bf16x8*)(&Pl[wv][q16][quad * 8]);

    const __bf16* Vb = (const __bf16*)Vl[buf];
    int vx = (quad ^ (q16 & 3)) << 3;
#pragma unroll
    for (int ds = 0; ds < 4; ++ds) {
      bf16x8 av = *(const bf16x8*)(Vb + (ds * 16 + q16) * 32 + vx);
      f32x4 c = accO[ds];
#pragma unroll
      for (int r = 0; r < 4; ++r) c[r] *= alpha;
      accO[ds] = __builtin_amdgcn_mfma_f32_16x16x32_bf16(av, ap, c, 0, 0, 0);
    }

    __syncthreads();
    buf ^= 1;
  }

  float rl = 1.0f / lsum;
  size_t rowbase = ((size_t)(b * NTOK) + i0 + q16) * DMODEL + h * 64;
#pragma unroll
  for (int ds = 0; ds < 4; ++ds) {
    int d0 = ds * 16 + quad * 4;
    u16x4 xv = *(const u16x4*)(xp + rowbase + d0);
    f32x4 ov;
#pragma unroll
    for (int r = 0; r < 4; ++r) ov[r] = b2f(xv[r]) + accO[ds][r] * rl;
    *(f32x4*)(x1 + rowbase + d0) = ov;
  }
}

extern "C" void kernel_launch(void* const* d_in, const int* in_sizes, int n_in,
                              void* d_out, int out_size, void* d_ws, size_t ws_size,
                              hipStream_t stream) {
  // ---- host-side boundary tripwires (verified passing in R6) ----
  static const int esz[13] = {3145728, 12288, 768, 768, 1769472, 2304, 36,
                              768, 768, 3145728, 4096, 1572864, 768};
  float sig = -1.f;
  if (n_in != 13) {
    sig = 6000.f + 100.f * (float)n_in;
  } else {
    for (int i = 0; i < 13; ++i)
      if (in_sizes[i] != esz[i]) { sig = 1000.f + 100.f * (float)i; break; }
  }
  if (sig < 0.f && ws_size < 57258496ULL) sig = 3000.f;
  if (sig < 0.f && out_size != 3145728) sig = 3100.f;
  if (sig >= 0.f) {
    signal_kernel<<<(out_size + 255) / 256, 256, 0, stream>>>((float*)d_out, out_size, sig);
    return;
  }

  char* ws = (char*)d_ws;
  int*  flag    = (int*)ws;                       // 256 B
  u16*  cx      = (u16*)(ws + 256);               // 6291456
  u16*  cqkvw   = (u16*)(ws + 6291712);           // 3538944
  u16*  cwinw   = (u16*)(ws + 9830656);           // 6291456
  u16*  cwoutw  = (u16*)(ws + 16122112);          // 3145728
  u16*  ccoords = (u16*)(ws + 19267840);          // 24576
  u16*  cln1g   = (u16*)(ws + 19292416);          // 1536
  u16*  cln1b   = (u16*)(ws + 19293952);          // 1536
  u16*  cqkvb   = (u16*)(ws + 19295488);          // 4608
  u16*  crelw   = (u16*)(ws + 19300096);          // 72 (padded)
  u16*  cln2g   = (u16*)(ws + 19300352);          // 1536
  u16*  cln2b   = (u16*)(ws + 19301888);          // 1536
  u16*  cwinb   = (u16*)(ws + 19303424);          // 8192
  u16*  cwoutb  = (u16*)(ws + 19311616);          // 1536
  u16*  h       = (u16*)(ws + 19313152);          // 6291456 (LN out; dead between
                                                  //  gemm_bt and ln2 -> reused as Vt)
  u16*  qkv     = (u16*)(ws + 25604608);          // 18874368 (reused as act)
  float* pbuf   = (float*)(ws + 44478976);        // 196608
  float* x1     = (float*)(ws + 44675584);        // 12582912 -> end 57258496
  u16*  act     = qkv;
  u16*  vt      = h;       // Vt needs 6291456 B == sizeof(h)
  // split-K partial: cx/cqkvw/cwinw region is dead after ffn_in (needs 12.6MB of 16.1MB)
  float* part   = (float*)(ws + 256);

  // 0a. dtype flag (f32 confirmed; adaptive kept as insurance)
  detect_kernel<<<1, 256, 0, stream>>>((const u16*)d_in[0], flag);

  // 0b. canonicalize all 13 inputs to bf16 (linear C-order)
  CanonJobs jobs;
  u16* dsts[13] = {cx, ccoords, cln1g, cln1b, cqkvw, cqkvb, crelw,
                   cln2g, cln2b, cwinw, cwinb, cwoutw, cwoutb};
  for (int i = 0; i < 13; ++i) {
    jobs.s[i] = d_in[i];
    jobs.d[i] = dsts[i];
    jobs.n[i] = in_sizes[i];
  }
  canon_kernel<<<dim3(3072, 13), 256, 0, stream>>>(jobs, flag);

  // 1. h = LN1(x)
  ln_bf16_kernel<<<4096, 256, 0, stream>>>(cx, cln1g, cln1b, h);
  // 2. qkv = h @ qkv_w^T + qkv_b   (M=4096, N=2304, K=768)
  gemm_bt<<<dim3(18, 32), 256, 0, stream>>>(h, cqkvw, cqkvb, qkv, 2304, 768);
  // 3. p2[b,h,n] (pre-scaled by LOG2E)
  p_kernel<<<16, 256, 0, stream>>>(ccoords, crelw, pbuf);
  // 3b. Vt[b][h][d][n] = V  (h buffer is dead here; gemm_bt already consumed it)
  vt_kernel<<<768, 256, 0, stream>>>(qkv, vt);
  // 4. x1 = x + attention(qkv, Vt, p2)   (768 blocks; block-cooperative staging)
  attn_kernel<<<768, 256, 0, stream>>>(qkv, vt, pbuf, cx, x1);
  // 5. h2 = LN2(x1)  (reuse h)
  ln_f32_kernel<<<4096, 256, 0, stream>>>(x1, cln2g, cln2b, h);
  // 6+7. act = silu(h2 @ Wu^T + bu) * (h2 @ Wg^T + bg)   (fused, LDS-staged)
  ffn_in_kernel<<<dim3(32, 32), 256, 0, stream>>>(h, cwinw, cwinb, act);
  // 8. out(F32) = x1 + act @ wout_w^T + wout_b   split-K x2 (768 blocks)
  gemm_out_split<<<dim3(12, 32, 2), 256, 0, stream>>>(act, cwoutw, cwoutb, x1,
                                                      part, (float*)d_out);
  // 8b. out += partial(kz=0)
  add_kernel<<<3072, 256, 0, stream>>>((float*)d_out, part);
}

// Round 7
// 289.221 us; speedup vs baseline: 1.5688x; 1.0140x over previous
//
#include <hip/hip_runtime.h>
#include <math.h>

typedef unsigned short u16;
typedef __bf16 bf16x8 __attribute__((ext_vector_type(8)));
typedef __bf16 bf16x4 __attribute__((ext_vector_type(4)));
typedef u16 u16x4 __attribute__((ext_vector_type(4)));
typedef float f32x4 __attribute__((ext_vector_type(4)));

// ---- constants ----
// B=4, N=1024, D=768, H=12, Dh=64, HID=2048, 3D=2304
#define NTOK 1024
#define DMODEL 768
#define NHEAD 12
#define LD3 2304
#define HIDDIM 2048

__device__ __forceinline__ float b2f(u16 u) {
  unsigned int t = ((unsigned int)u) << 16;
  float f;
  __builtin_memcpy(&f, &t, 4);
  return f;
}
__device__ __forceinline__ u16 f2b(float f) {
  unsigned int t;
  __builtin_memcpy(&t, &f, 4);
  t += 0x7fffu + ((t >> 16) & 1u);
  return (u16)(t >> 16);
}

// async global->LDS, 16B per lane; LDS dest is wave-uniform base + lane*16
__device__ __forceinline__ void gl_lds16(const u16* g, u16* l) {
  __builtin_amdgcn_global_load_lds(
      (__attribute__((address_space(1))) const unsigned int*)g,
      (__attribute__((address_space(3))) unsigned int*)l, 16, 0, 0);
}

// ---------------- host-assert signal (f32 output now) ------------------------
__global__ __launch_bounds__(256) void signal_kernel(float* __restrict__ out,
                                                     int n, float c) {
  int i = blockIdx.x * 256 + threadIdx.x;
  if (i < n) out[i] = c;
}

// ---------------- input dtype detection (verified f32: flag=1, R6) -----------
__global__ __launch_bounds__(256) void detect_kernel(const u16* __restrict__ x,
                                                     int* __restrict__ flag) {
  __shared__ int cnt;
  if (threadIdx.x == 0) cnt = 0;
  __syncthreads();
  int bad = 0;
  for (int i = threadIdx.x; i < 4096; i += 256) {
    u16 v = x[2 * i];
    int e = (v >> 7) & 0xFF;
    if (e >= 0xC0) bad++;
  }
  atomicAdd(&cnt, bad);
  __syncthreads();
  if (threadIdx.x == 0) *flag = (cnt >= 64) ? 1 : 0;
}

// ---------------- canonicalize all inputs to bf16 (linear, C-order) ----------
struct CanonJobs {
  const void* s[13];
  u16* d[13];
  int n[13];
};

__global__ __launch_bounds__(256) void canon_kernel(CanonJobs jobs,
                                                    const int* __restrict__ flag) {
  int j = blockIdx.y;
  int n = jobs.n[j];
  const void* s = jobs.s[j];
  u16* d = jobs.d[j];
  bool isf32 = (*flag != 0);
  for (int i = blockIdx.x * 256 + threadIdx.x; i < n; i += gridDim.x * 256) {
    d[i] = isf32 ? f2b(((const float*)s)[i]) : ((const u16*)s)[i];
  }
}

// ---------------- LayerNorm (bf16 input) ----------------
__global__ __launch_bounds__(256) void ln_bf16_kernel(
    const u16* __restrict__ x, const u16* __restrict__ g,
    const u16* __restrict__ b, u16* __restrict__ out) {
  int row = blockIdx.x;
  int tid = threadIdx.x;
  const u16* xr = x + (size_t)row * DMODEL;
  float v0 = b2f(xr[tid]), v1 = b2f(xr[tid + 256]), v2 = b2f(xr[tid + 512]);
  float s = v0 + v1 + v2;
  float q = v0 * v0 + v1 * v1 + v2 * v2;
#pragma unroll
  for (int off = 32; off; off >>= 1) {
    s += __shfl_xor(s, off, 64);
    q += __shfl_xor(q, off, 64);
  }
  __shared__ float rs[4], rq[4];
  int wv = tid >> 6;
  if ((tid & 63) == 0) { rs[wv] = s; rq[wv] = q; }
  __syncthreads();
  s = rs[0] + rs[1] + rs[2] + rs[3];
  q = rq[0] + rq[1] + rq[2] + rq[3];
  float mean = s * (1.0f / 768.0f);
  float var = q * (1.0f / 768.0f) - mean * mean;
  float inv = rsqrtf(var + 1e-5f);
  u16* outr = out + (size_t)row * DMODEL;
  outr[tid]       = f2b((v0 - mean) * inv * b2f(g[tid])       + b2f(b[tid]));
  outr[tid + 256] = f2b((v1 - mean) * inv * b2f(g[tid + 256]) + b2f(b[tid + 256]));
  outr[tid + 512] = f2b((v2 - mean) * inv * b2f(g[tid + 512]) + b2f(b[tid + 512]));
}

// ---------------- LayerNorm (f32 input) ----------------
__global__ __launch_bounds__(256) void ln_f32_kernel(
    const float* __restrict__ x, const u16* __restrict__ g,
    const u16* __restrict__ b, u16* __restrict__ out) {
  int row = blockIdx.x;
  int tid = threadIdx.x;
  const float* xr = x + (size_t)row * DMODEL;
  float v0 = xr[tid], v1 = xr[tid + 256], v2 = xr[tid + 512];
  float s = v0 + v1 + v2;
  float q = v0 * v0 + v1 * v1 + v2 * v2;
#pragma unroll
  for (int off = 32; off; off >>= 1) {
    s += __shfl_xor(s, off, 64);
    q += __shfl_xor(q, off, 64);
  }
  __shared__ float rs[4], rq[4];
  int wv = tid >> 6;
  if ((tid & 63) == 0) { rs[wv] = s; rq[wv] = q; }
  __syncthreads();
  s = rs[0] + rs[1] + rs[2] + rs[3];
  q = rq[0] + rq[1] + rq[2] + rq[3];
  float mean = s * (1.0f / 768.0f);
  float var = q * (1.0f / 768.0f) - mean * mean;
  float inv = rsqrtf(var + 1e-5f);
  u16* outr = out + (size_t)row * DMODEL;
  outr[tid]       = f2b((v0 - mean) * inv * b2f(g[tid])       + b2f(b[tid]));
  outr[tid + 256] = f2b((v1 - mean) * inv * b2f(g[tid + 256]) + b2f(b[tid + 256]));
  outr[tid + 512] = f2b((v2 - mean) * inv * b2f(g[tid + 512]) + b2f(b[tid + 512]));
}

// ====== shared LDS-staged 128x128 mainloop (m97 structure) ======
__device__ __forceinline__ void gemm128_mainloop(
    const u16* __restrict__ A, const u16* __restrict__ W, int K,
    int mB0, int nB0, u16* Al, u16* Bl, f32x4 (&acc)[4][4]) {
  int lane = threadIdx.x & 63;
  int wv = threadIdx.x >> 6;
  int q16 = lane & 15, quad = lane >> 4;
  int mW = (wv >> 1) * 64, nW = (wv & 1) * 64;
  int srow = lane >> 2, scol = (lane & 3) * 8;
  for (int k0 = 0; k0 < K; k0 += 32) {
#pragma unroll
    for (int c = 0; c < 2; ++c) {
      int ch = wv * 2 + c;
      int r = ch * 16 + srow;
      gl_lds16(A + (size_t)(mB0 + r) * K + k0 + scol, Al + ch * 512);
      gl_lds16(W + (size_t)(nB0 + r) * K + k0 + scol, Bl + ch * 512);
    }
    __syncthreads();
    bf16x8 af[4], bfr[4];
#pragma unroll
    for (int si = 0; si < 4; ++si)
      af[si] = *(const bf16x8*)((const __bf16*)Al + (mW + si * 16 + q16) * 32 + quad * 8);
#pragma unroll
    for (int sj = 0; sj < 4; ++sj)
      bfr[sj] = *(const bf16x8*)((const __bf16*)Bl + (nW + sj * 16 + q16) * 32 + quad * 8);
#pragma unroll
    for (int si = 0; si < 4; ++si)
#pragma unroll
      for (int sj = 0; sj < 4; ++sj)
        acc[si][sj] = __builtin_amdgcn_mfma_f32_16x16x32_bf16(af[si], bfr[sj], acc[si][sj], 0, 0, 0);
    __syncthreads();
  }
}

// ---------------- MFMA GEMM: C = A[M,K] * W[N,K]^T + bias, bf16 out ----------
__global__ __launch_bounds__(256) void gemm_bt(
    const u16* __restrict__ Ap, const u16* __restrict__ Wp,
    const u16* __restrict__ bias, u16* __restrict__ Cp, int Nn, int K) {
  __shared__ __align__(16) u16 Al[128 * 32], Bl[128 * 32];
  int lane = threadIdx.x & 63;
  int wv = threadIdx.x >> 6;
  int q16 = lane & 15, quad = lane >> 4;
  int mBase = blockIdx.y * 128 + (wv >> 1) * 64;
  int nBase = blockIdx.x * 128 + (wv & 1) * 64;
  f32x4 acc[4][4] = {};
  gemm128_mainloop(Ap, Wp, K, blockIdx.y * 128, blockIdx.x * 128, Al, Bl, acc);
#pragma unroll
  for (int si = 0; si < 4; ++si)
#pragma unroll
    for (int sj = 0; sj < 4; ++sj) {
      int col = nBase + sj * 16 + q16;
      float bcol = b2f(bias[col]);
#pragma unroll
      for (int r = 0; r < 4; ++r) {
        int rowi = mBase + si * 16 + quad * 4 + r;
        Cp[(size_t)rowi * Nn + col] = f2b(acc[si][sj][r] + bcol);
      }
    }
}

// ---------------- final GEMM, split-K x 2, N-tile 64: 768 blocks -------------
__global__ __launch_bounds__(256) void gemm_out_split(
    const u16* __restrict__ Ap, const u16* __restrict__ Wp,
    const u16* __restrict__ bias, const float* __restrict__ res,
    float* __restrict__ part, float* __restrict__ out) {
  __shared__ __align__(16) u16 Al[128 * 32], Bl[64 * 32];
  int lane = threadIdx.x & 63;
  int wv = threadIdx.x >> 6;
  int q16 = lane & 15, quad = lane >> 4;
  int mB0 = blockIdx.y * 128;
  int nB0 = blockIdx.x * 64;
  int kz = blockIdx.z;
  int kbase = kz * 1024;
  int mW = (wv >> 1) * 64, nW = (wv & 1) * 32;
  int srow = lane >> 2, scol = (lane & 3) * 8;
  f32x4 acc[4][2] = {};
  for (int k0 = 0; k0 < 1024; k0 += 32) {
#pragma unroll
    for (int c = 0; c < 2; ++c) {
      int ch = wv * 2 + c;
      int r = ch * 16 + srow;
      gl_lds16(Ap + (size_t)(mB0 + r) * 2048 + kbase + k0 + scol, Al + ch * 512);
    }
    {
      int r = wv * 16 + srow;
      gl_lds16(Wp + (size_t)(nB0 + r) * 2048 + kbase + k0 + scol, Bl + wv * 512);
    }
    __syncthreads();
    bf16x8 af[4], bfr[2];
#pragma unroll
    for (int si = 0; si < 4; ++si)
      af[si] = *(const bf16x8*)((const __bf16*)Al + (mW + si * 16 + q16) * 32 + quad * 8);
#pragma unroll
    for (int sj = 0; sj < 2; ++sj)
      bfr[sj] = *(const bf16x8*)((const __bf16*)Bl + (nW + sj * 16 + q16) * 32 + quad * 8);
#pragma unroll
    for (int si = 0; si < 4; ++si)
#pragma unroll
      for (int sj = 0; sj < 2; ++sj)
        acc[si][sj] = __builtin_amdgcn_mfma_f32_16x16x32_bf16(af[si], bfr[sj], acc[si][sj], 0, 0, 0);
    __syncthreads();
  }
#pragma unroll
  for (int si = 0; si < 4; ++si)
#pragma unroll
    for (int sj = 0; sj < 2; ++sj) {
      int col = nB0 + nW + sj * 16 + q16;
#pragma unroll
      for (int r = 0; r < 4; ++r) {
        int rowi = mB0 + mW + si * 16 + quad * 4 + r;
        size_t idx = (size_t)rowi * 768 + col;
        if (kz == 0) {
          part[idx] = acc[si][sj][r];
        } else {
          out[idx] = acc[si][sj][r] + b2f(bias[col]) + res[idx];
        }
      }
    }
}

// ---------------- out += part (vectorized, 3.1M floats) ----------------------
__global__ __launch_bounds__(256) void add_kernel(float* __restrict__ out,
                                                  const float* __restrict__ part) {
  int i = blockIdx.x * 256 + threadIdx.x;   // 786432 f32x4 elems -> 3072 blocks
  f32x4 o = ((f32x4*)out)[i];
  f32x4 p = ((const f32x4*)part)[i];
#pragma unroll
  for (int r = 0; r < 4; ++r) o[r] += p[r];
  ((f32x4*)out)[i] = o;
}

// ---------------- fused FFN-in: act = silu(h2 @ Wu^T + bu) * (h2 @ Wg^T + bg)
__global__ __launch_bounds__(256) void ffn_in_kernel(
    const u16* __restrict__ hp, const u16* __restrict__ Wp,
    const u16* __restrict__ bias, u16* __restrict__ actp) {
  __shared__ __align__(16) u16 Al[128 * 32], Bl[128 * 32];
  int lane = threadIdx.x & 63;
  int wv = threadIdx.x >> 6;
  int q16 = lane & 15, quad = lane >> 4;
  int mB0 = blockIdx.y * 128;
  int cB0 = blockIdx.x * 64;
  int mW = (wv >> 1) * 64;
  int cW = (wv & 1) * 32;
  int srow = lane >> 2, scol = (lane & 3) * 8;
  f32x4 au[4][2] = {}, ag[4][2] = {};
  for (int k0 = 0; k0 < DMODEL; k0 += 32) {
#pragma unroll
    for (int c = 0; c < 2; ++c) {
      int ch = wv * 2 + c;
      int r = ch * 16 + srow;
      gl_lds16(hp + (size_t)(mB0 + r) * DMODEL + k0 + scol, Al + ch * 512);
      int grow = (r < 64) ? (cB0 + r) : (HIDDIM + cB0 + r - 64);
      gl_lds16(Wp + (size_t)grow * DMODEL + k0 + scol, Bl + ch * 512);
    }
    __syncthreads();
    bf16x8 af[4], wu[2], wg[2];
#pragma unroll
    for (int si = 0; si < 4; ++si)
      af[si] = *(const bf16x8*)((const __bf16*)Al + (mW + si * 16 + q16) * 32 + quad * 8);
#pragma unroll
    for (int sj = 0; sj < 2; ++sj) {
      wu[sj] = *(const bf16x8*)((const __bf16*)Bl + (cW + sj * 16 + q16) * 32 + quad * 8);
      wg[sj] = *(const bf16x8*)((const __bf16*)Bl + (64 + cW + sj * 16 + q16) * 32 + quad * 8);
    }
#pragma unroll
    for (int si = 0; si < 4; ++si)
#pragma unroll
      for (int sj = 0; sj < 2; ++sj) {
        au[si][sj] = __builtin_amdgcn_mfma_f32_16x16x32_bf16(af[si], wu[sj], au[si][sj], 0, 0, 0);
        ag[si][sj] = __builtin_amdgcn_mfma_f32_16x16x32_bf16(af[si], wg[sj], ag[si][sj], 0, 0, 0);
      }
    __syncthreads();
  }
#pragma unroll
  for (int si = 0; si < 4; ++si)
#pragma unroll
    for (int sj = 0; sj < 2; ++sj) {
      int col = cB0 + cW + sj * 16 + q16;
      float bu = b2f(bias[col]);
      float bg = b2f(bias[HIDDIM + col]);
#pragma unroll
      for (int r = 0; r < 4; ++r) {
        int rowi = mB0 + mW + si * 16 + quad * 4 + r;
        float u = au[si][sj][r] + bu;
        float g = ag[si][sj][r] + bg;
        float s = u / (1.0f + __expf(-u));
        actp[(size_t)rowi * HIDDIM + col] = f2b(s * g);
      }
    }
}

// ---------------- coord bias p2[b,h,n] = (coords.relw) * LOG2E ---------------
__global__ __launch_bounds__(256) void p_kernel(
    const u16* __restrict__ coords, const u16* __restrict__ relw,
    float* __restrict__ p) {
  const float LOG2E = 1.4426950408889634f;
  int idx = blockIdx.x * 256 + threadIdx.x;  // B*N = 4096
  float c0 = b2f(coords[idx * 3 + 0]);
  float c1 = b2f(coords[idx * 3 + 1]);
  float c2 = b2f(coords[idx * 3 + 2]);
  int b = idx >> 10, n = idx & 1023;
#pragma unroll
  for (int h = 0; h < NHEAD; ++h) {
    float w0 = b2f(relw[h * 3 + 0]), w1 = b2f(relw[h * 3 + 1]), w2 = b2f(relw[h * 3 + 2]);
    p[(size_t)(b * NHEAD + h) * NTOK + n] = (c0 * w0 + c1 * w1 + c2 * w2) * LOG2E;
  }
}

// ---------------- V transpose: Vt[b][h][d][n] = V[b][n][h][d] ----------------
__global__ __launch_bounds__(256) void vt_kernel(const u16* __restrict__ qkvp,
                                                 u16* __restrict__ vtp) {
  int blk = blockIdx.x;            // b*192 + h*16 + nt
  int b = blk / 192;
  int rem = blk % 192;
  int h = rem >> 4;
  int nt = rem & 15;
  int wv = threadIdx.x >> 6;
  int d = threadIdx.x & 63;
  int n0 = nt * 64 + wv * 16;
  const u16* src = qkvp + ((size_t)(b * NTOK) + n0) * LD3 + 2 * DMODEL + h * 64 + d;
  u16* dst = vtp + ((size_t)((b * NHEAD + h) * 64 + d)) * NTOK + n0;
#pragma unroll
  for (int c = 0; c < 2; ++c) {
    u16 buf[8] __attribute__((aligned(16)));
#pragma unroll
    for (int i = 0; i < 8; ++i) buf[i] = src[(size_t)(c * 8 + i) * LD3];
    *(uint4*)(dst + c * 8) = *(const uint4*)buf;
  }
}

// ---------------- flash attention: XCD-local heads, 4-deep counted pipeline --
// blockIdx swizzle: head g = hw%48, tile nt = hw/48. 48 == 0 mod 8, so all 16
// blocks of a head share hw%8 -> same XCD -> per-head K/V is L2-resident.
// 4-buffer ring staged 3 tiles ahead; per iter: s_waitcnt vmcnt(4) (keeps the
// 2 youngest tile-stages in flight) BEFORE raw s_barrier (so barrier release
// implies every wave's tile-t stage landed); stage(t+3) issued AFTER the
// barrier into the buffer all waves finished reading at t-1. p-row staged to
// LDS once so the loop's vmcnt stream contains only staging ops.
__global__ __launch_bounds__(256) void attn_kernel(
    const u16* __restrict__ qkvp, const u16* __restrict__ vtp,
    const float* __restrict__ p2, const u16* __restrict__ xp,
    float* __restrict__ x1) {
  const __bf16* qb = (const __bf16*)qkvp;
  __shared__ __align__(16) u16 Kl[4][32 * 64];   // [j][d], 16B-slot swz by j&7
  __shared__ __align__(16) u16 Vl[4][64 * 32];   // [d][j], 16B-slot swz by d&3
  __shared__ __align__(16) u16 Pl[4][16][40];    // 80B row stride
  __shared__ __align__(16) float Pb[1024];       // p-row (pre-scaled by LOG2E)
  int lane = threadIdx.x & 63;
  int wv = threadIdx.x >> 6;
  int hw = blockIdx.x;                     // 0..767
  int g = hw % 48;                         // (b,h): all its 16 tiles same XCD
  int nt = hw / 48;                        // query-tile group 0..15
  int b = g / 12, h = g % 12;
  int i0 = (nt * 4 + wv) * 16;             // wave's query tile
  int q16 = lane & 15, quad = lane >> 4;

  const float scl2 = 0.125f * 1.4426950408889634f;

  const __bf16* qrow = qb + ((size_t)(b * NTOK) + i0 + q16) * LD3 + h * 64;
  bf16x8 bq0 = *(const bf16x8*)(qrow + quad * 8);
  bf16x8 bq1 = *(const bf16x8*)(qrow + 32 + quad * 8);

  const float* prow = p2 + (size_t)(b * NHEAD + h) * NTOK;

  int krw = wv * 8 + (lane >> 3);          // K row 0..31 this lane stages
  int ks  = (lane & 7) ^ (krw & 7);        // swizzled 16B slot (8 per 128B row)
  const u16* kg0 = qkvp + (size_t)(b * NTOK) * LD3 + DMODEL + h * 64 + ks * 8;
  int vrw = wv * 16 + (lane >> 2);         // Vt row (d) 0..63
  int vs  = (lane & 3) ^ (vrw & 3);        // swizzled 16B slot (4 per 64B row)
  const u16* vg0 = vtp + ((size_t)((b * NHEAD + h) * 64 + vrw)) * NTOK + vs * 8;

  float mrun = -1e30f, lsum = 0.f;
  f32x4 accO[4] = {};

  // prologue: p-row + tiles 0..2 (7 outstanding loads/wave)
  gl_lds16((const u16*)(prow + wv * 256 + lane * 4), (u16*)&Pb[wv * 256]);
#pragma unroll
  for (int tt = 0; tt < 3; ++tt) {
    gl_lds16(kg0 + (size_t)(tt * 32 + krw) * LD3, &Kl[tt][wv * 512]);
    gl_lds16(vg0 + tt * 32, &Vl[tt][wv * 512]);
  }

  for (int t = 0; t < 32; ++t) {
    // wait for own stage(t) [+p on t=0]; in-order retire => oldest first.
    if (t < 30)       asm volatile("s_waitcnt vmcnt(4)" ::: "memory");
    else if (t == 30) asm volatile("s_waitcnt vmcnt(2)" ::: "memory");
    else              asm volatile("s_waitcnt vmcnt(0)" ::: "memory");
    __builtin_amdgcn_sched_barrier(0);
    __builtin_amdgcn_s_barrier();            // all waves' stage(t) landed
    __builtin_amdgcn_sched_barrier(0);
    if (t < 29) {                            // stage(t+3) into buf (t-1)&3
      int j = (t + 3) * 32;
      gl_lds16(kg0 + (size_t)(j + krw) * LD3, &Kl[(t + 3) & 3][wv * 512]);
      gl_lds16(vg0 + j, &Vl[(t + 3) & 3][wv * 512]);
    }

    int j0 = t * 32;
    const __bf16* Kb = (const __bf16*)Kl[t & 3];
    int kx0 = (quad ^ (q16 & 7)) << 3;
    int kx1 = ((4 | quad) ^ (q16 & 7)) << 3;
    bf16x8 ka00 = *(const bf16x8*)(Kb + q16 * 64 + kx0);
    bf16x8 ka01 = *(const bf16x8*)(Kb + q16 * 64 + kx1);
    bf16x8 ka10 = *(const bf16x8*)(Kb + (16 + q16) * 64 + kx0);
    bf16x8 ka11 = *(const bf16x8*)(Kb + (16 + q16) * 64 + kx1);
    f32x4 st0 = {}, st1 = {};
    st0 = __builtin_amdgcn_mfma_f32_16x16x32_bf16(ka00, bq0, st0, 0, 0, 0);
    st0 = __builtin_amdgcn_mfma_f32_16x16x32_bf16(ka01, bq1, st0, 0, 0, 0);
    st1 = __builtin_amdgcn_mfma_f32_16x16x32_bf16(ka10, bq0, st1, 0, 0, 0);
    st1 = __builtin_amdgcn_mfma_f32_16x16x32_bf16(ka11, bq1, st1, 0, 0, 0);

    f32x4 pjl = *(const f32x4*)(&Pb[j0 + 4 * quad]);
    f32x4 pjh = *(const f32x4*)(&Pb[j0 + 16 + 4 * quad]);
    float sl[4], sh[4];
#pragma unroll
    for (int r = 0; r < 4; ++r) {
      sl[r] = st0[r] * scl2 - pjl[r];
      sh[r] = st1[r] * scl2 - pjh[r];
    }
    float lm = fmaxf(fmaxf(fmaxf(sl[0], sl[1]), fmaxf(sl[2], sl[3])),
                     fmaxf(fmaxf(sh[0], sh[1]), fmaxf(sh[2], sh[3])));
    lm = fmaxf(lm, __shfl_xor(lm, 16, 64));
    lm = fmaxf(lm, __shfl_xor(lm, 32, 64));
    float mn = fmaxf(mrun, lm);
    float alpha = exp2f(mrun - mn);
    mrun = mn;
    float pl[4], ph[4];
#pragma unroll
    for (int r = 0; r < 4; ++r) {
      pl[r] = exp2f(sl[r] - mn);
      ph[r] = exp2f(sh[r] - mn);
    }
    float ts = (pl[0] + pl[1]) + (pl[2] + pl[3]) +
               (ph[0] + ph[1]) + (ph[2] + ph[3]);
    ts += __shfl_xor(ts, 16, 64);
    ts += __shfl_xor(ts, 32, 64);
    lsum = lsum * alpha + ts;

    bf16x4 w0 = {(__bf16)pl[0], (__bf16)pl[1], (__bf16)pl[2], (__bf16)pl[3]};
    bf16x4 w1 = {(__bf16)ph[0], (__bf16)ph[1], (__bf16)ph[2], (__bf16)ph[3]};
    *(bf16x4*)(&Pl[wv][q16][4 * quad]) = w0;
    *(bf16x4*)(&Pl[wv][q16][16 + 4 * quad]) = w1;
    bf16x8 ap = *(const bf16x8*)(&Pl[wv][q16][quad * 8]);  // wave-private

    const __bf16* Vb = (const __bf16*)Vl[t & 3];
    int vx = (quad ^ (q16 & 3)) << 3;
#pragma unroll
    for (int ds = 0; ds < 4; ++ds) {
      bf16x8 av = *(const bf16x8*)(Vb + (ds * 16 + q16) * 32 + vx);
      f32x4 c = accO[ds];
#pragma unroll
      for (int r = 0; r < 4; ++r) c[r] *= alpha;
      accO[ds] = __builtin_amdgcn_mfma_f32_16x16x32_bf16(av, ap, c, 0, 0, 0);
    }
  }

  float rl = 1.0f / lsum;
  size_t rowbase = ((size_t)(b * NTOK) + i0 + q16) * DMODEL + h * 64;
#pragma unroll
  for (int ds = 0; ds < 4; ++ds) {
    int d0 = ds * 16 + quad * 4;
    u16x4 xv = *(const u16x4*)(xp + rowbase + d0);
    f32x4 ov;
#pragma unroll
    for (int r = 0; r < 4; ++r) ov[r] = b2f(xv[r]) + accO[ds][r] * rl;
    *(f32x4*)(x1 + rowbase + d0) = ov;
  }
}

extern "C" void kernel_launch(void* const* d_in, const int* in_sizes, int n_in,
                              void* d_out, int out_size, void* d_ws, size_t ws_size,
                              hipStream_t stream) {
  // ---- host-side boundary tripwires (verified passing in R6) ----
  static const int esz[13] = {3145728, 12288, 768, 768, 1769472, 2304, 36,
                              768, 768, 3145728, 4096, 1572864, 768};
  float sig = -1.f;
  if (n_in != 13) {
    sig = 6000.f + 100.f * (float)n_in;
  } else {
    for (int i = 0; i < 13; ++i)
      if (in_sizes[i] != esz[i]) { sig = 1000.f + 100.f * (float)i; break; }
  }
  if (sig < 0.f && ws_size < 57258496ULL) sig = 3000.f;
  if (sig < 0.f && out_size != 3145728) sig = 3100.f;
  if (sig >= 0.f) {
    signal_kernel<<<(out_size + 255) / 256, 256, 0, stream>>>((float*)d_out, out_size, sig);
    return;
  }

  char* ws = (char*)d_ws;
  int*  flag    = (int*)ws;                       // 256 B
  u16*  cx      = (u16*)(ws + 256);               // 6291456
  u16*  cqkvw   = (u16*)(ws + 6291712);           // 3538944
  u16*  cwinw   = (u16*)(ws + 9830656);           // 6291456
  u16*  cwoutw  = (u16*)(ws + 16122112);          // 3145728
  u16*  ccoords = (u16*)(ws + 19267840);          // 24576
  u16*  cln1g   = (u16*)(ws + 19292416);          // 1536
  u16*  cln1b   = (u16*)(ws + 19293952);          // 1536
  u16*  cqkvb   = (u16*)(ws + 19295488);          // 4608
  u16*  crelw   = (u16*)(ws + 19300096);          // 72 (padded)
  u16*  cln2g   = (u16*)(ws + 19300352);          // 1536
  u16*  cln2b   = (u16*)(ws + 19301888);          // 1536
  u16*  cwinb   = (u16*)(ws + 19303424);          // 8192
  u16*  cwoutb  = (u16*)(ws + 19311616);          // 1536
  u16*  h       = (u16*)(ws + 19313152);          // 6291456 (LN out; dead between
                                                  //  gemm_bt and ln2 -> reused as Vt)
  u16*  qkv     = (u16*)(ws + 25604608);          // 18874368 (reused as act)
  float* pbuf   = (float*)(ws + 44478976);        // 196608
  float* x1     = (float*)(ws + 44675584);        // 12582912 -> end 57258496
  u16*  act     = qkv;
  u16*  vt      = h;       // Vt needs 6291456 B == sizeof(h)
  // split-K partial: cx/cqkvw/cwinw region is dead after ffn_in (needs 12.6MB of 16.1MB)
  float* part   = (float*)(ws + 256);

  // 0a. dtype flag (f32 confirmed; adaptive kept as insurance)
  detect_kernel<<<1, 256, 0, stream>>>((const u16*)d_in[0], flag);

  // 0b. canonicalize all 13 inputs to bf16 (linear C-order)
  CanonJobs jobs;
  u16* dsts[13] = {cx, ccoords, cln1g, cln1b, cqkvw, cqkvb, crelw,
                   cln2g, cln2b, cwinw, cwinb, cwoutw, cwoutb};
  for (int i = 0; i < 13; ++i) {
    jobs.s[i] = d_in[i];
    jobs.d[i] = dsts[i];
    jobs.n[i] = in_sizes[i];
  }
  canon_kernel<<<dim3(3072, 13), 256, 0, stream>>>(jobs, flag);

  // 1. h = LN1(x)
  ln_bf16_kernel<<<4096, 256, 0, stream>>>(cx, cln1g, cln1b, h);
  // 2. qkv = h @ qkv_w^T + qkv_b   (M=4096, N=2304, K=768)
  gemm_bt<<<dim3(18, 32), 256, 0, stream>>>(h, cqkvw, cqkvb, qkv, 2304, 768);
  // 3. p2[b,h,n] (pre-scaled by LOG2E)
  p_kernel<<<16, 256, 0, stream>>>(ccoords, crelw, pbuf);
  // 3b. Vt[b][h][d][n] = V  (h buffer is dead here; gemm_bt already consumed it)
  vt_kernel<<<768, 256, 0, stream>>>(qkv, vt);
  // 4. x1 = x + attention(qkv, Vt, p2)   (768 blocks; XCD-local + deep pipeline)
  attn_kernel<<<768, 256, 0, stream>>>(qkv, vt, pbuf, cx, x1);
  // 5. h2 = LN2(x1)  (reuse h)
  ln_f32_kernel<<<4096, 256, 0, stream>>>(x1, cln2g, cln2b, h);
  // 6+7. act = silu(h2 @ Wu^T + bu) * (h2 @ Wg^T + bg)   (fused, LDS-staged)
  ffn_in_kernel<<<dim3(32, 32), 256, 0, stream>>>(h, cwinw, cwinb, act);
  // 8. out(F32) = x1 + act @ wout_w^T + wout_b   split-K x2 (768 blocks)
  gemm_out_split<<<dim3(12, 32, 2), 256, 0, stream>>>(act, cwoutw, cwoutb, x1,
                                                      part, (float*)d_out);
  // 8b. out += partial(kz=0)
  add_kernel<<<3072, 256, 0, stream>>>((float*)d_out, part);
}